// Round 4
// baseline (426.062 us; speedup 1.0000x reference)
//
#include <hip/hip_runtime.h>
#include <hip/hip_fp16.h>
#include <stdint.h>

#define NN 50000
#define NE 800000
#define NG 256
#define NBUCKET 16
#define PARTSZ (NBUCKET * 256)

// edge-slicing params
#define ABLK 391
#define ASLICE 2048

__device__ __forceinline__ unsigned short f2h(float f) {
    __half h = __float2half(f);
    return *(unsigned short*)&h;
}
__device__ __forceinline__ float h2f(unsigned short u) {
    __half h = *(__half*)&u;
    return __half2float(h);
}

#define AFF4(u, sc, sh) { u.x = fmaxf(sc.x*u.x+sh.x,0.f); u.y = fmaxf(sc.y*u.y+sh.y,0.f); \
                          u.z = fmaxf(sc.z*u.z+sh.z,0.f); u.w = fmaxf(sc.w*u.w+sh.w,0.f); }

// BN coefficients from double-precision partial sums (replay-stable)
__device__ __forceinline__ void bn_coef(const double* __restrict__ partIn,
                                        const float* __restrict__ gmv,
                                        const float* __restrict__ btv,
                                        int tid, int n, float* scs, float* shs) {
    double s = 0., q = 0.;
#pragma unroll
    for (int b2 = 0; b2 < NBUCKET; ++b2) {
        s += partIn[b2 * 256 + tid];
        q += partIn[b2 * 256 + 128 + tid];
    }
    double mu = s / (double)n;
    double var = q / (double)n - mu * mu;
    float a = gmv[tid] * rsqrtf((float)var + 1e-5f);
    scs[tid] = a;
    shs[tid] = btv[tid] - (float)mu * a;
}

// ---------------- prologue: direct CSR build ----------------
// kC1: per-node {count, sum_w} packed in one u64 atomic (count in bits 40+,
// weight fixed-point 2^-20 in low 40 bits); also zeroes part+pooled (doubles).
__global__ void kC1(const int* __restrict__ col, const float* __restrict__ ew,
                    unsigned long long* __restrict__ cd, double* __restrict__ zz,
                    int zn, int e) {
    int tid = threadIdx.x;
    for (int i = blockIdx.x * 256 + tid; i < zn; i += ABLK * 256) zz[i] = 0.;
    int start = blockIdx.x * ASLICE;
    int end = min(start + ASLICE, e);
    for (int i = start + tid; i < end; i += 256) {
        int c = col[i];
        unsigned long long v = (1ull << 40) |
            (unsigned long long)(unsigned)(ew[i] * 1048576.f + 0.5f);
        atomicAdd(&cd[c], v);
    }
}

// kC2g: block 0 = tiled exclusive scan of counts -> ptr/cur (50K nodes);
// blocks 1.. = gemm1 (x @ W1 : 128->16), overlapped with the serial scan.
__global__ void __launch_bounds__(1024) kC2g(
        const unsigned long long* __restrict__ cd, int* __restrict__ ptr,
        int* __restrict__ cur, const float* __restrict__ x,
        const float* __restrict__ W0, float* __restrict__ m1, int n) {
    __shared__ int wsum[16];
    __shared__ int carry_s;
    __shared__ float Wl[128 * 16];
    int tid = threadIdx.x;
    if (blockIdx.x == 0) {
        int lane = tid & 63, wid = tid >> 6;
        if (tid == 0) carry_s = 0;
        __syncthreads();
        const int NP = NN / 2;                 // 25000 ulonglong2 pairs
        const int NT = (NP + 1023) / 1024;     // 25 tiles
        for (int t = 0; t < NT; ++t) {
            int i2 = t * 1024 + tid;
            int c0 = 0, c1 = 0;
            if (i2 < NP) {
                ulonglong2 v = ((const ulonglong2*)cd)[i2];
                c0 = (int)(v.x >> 40);
                c1 = (int)(v.y >> 40);
            }
            int s = c0 + c1;
            int inc = s;
            for (int off = 1; off < 64; off <<= 1) {
                int tv = __shfl_up(inc, off, 64);
                if (lane >= off) inc += tv;
            }
            if (lane == 63) wsum[wid] = inc;
            __syncthreads();
            if (wid == 0) {
                int xv = (lane < 16) ? wsum[lane] : 0;
                for (int off = 1; off < 16; off <<= 1) {
                    int tv = __shfl_up(xv, off, 64);
                    if (lane >= off) xv += tv;
                }
                if (lane < 16) wsum[lane] = xv;
            }
            __syncthreads();
            int base = carry_s + (wid ? wsum[wid - 1] : 0) + (inc - s);
            if (i2 < NP) {
                int2 o;
                o.x = base; o.y = base + c0;
                ((int2*)ptr)[i2] = o;
                ((int2*)cur)[i2] = o;
            }
            __syncthreads();
            if (tid == 0) carry_s += wsum[15];
            __syncthreads();
        }
        if (tid == 0) ptr[NN] = carry_s;
        return;
    }
    // gemm1: 1024 threads, 4 lanes per node-slice, 2 nodes per group
    int bid = (int)blockIdx.x - 1;
    for (int i = tid; i < 128 * 16 / 4; i += 1024)
        ((float4*)Wl)[i] = ((const float4*)W0)[i];
    __syncthreads();
    int jq = tid & 3, group = tid >> 2;           // 256 groups
    int node0 = (bid * 256 + group) * 2;
    const float4* h4 = (const float4*)x;
    int hb[2]; bool val[2];
#pragma unroll
    for (int i = 0; i < 2; ++i) {
        int nd = node0 + i;
        val[i] = nd < n;
        hb[i] = (val[i] ? nd : n - 1) * 32;
    }
    float4 acc[2];
    acc[0] = {0,0,0,0}; acc[1] = {0,0,0,0};
#pragma unroll 4
    for (int k4 = 0; k4 < 32; ++k4) {
        const float* wb = &Wl[(k4 * 4) * 16 + jq * 4];
        float4 w0 = *(const float4*)(wb);
        float4 w1 = *(const float4*)(wb + 16);
        float4 w2 = *(const float4*)(wb + 32);
        float4 w3 = *(const float4*)(wb + 48);
#pragma unroll
        for (int i = 0; i < 2; ++i) {
            float4 hv = h4[hb[i] + k4];
            acc[i].x += hv.x*w0.x + hv.y*w1.x + hv.z*w2.x + hv.w*w3.x;
            acc[i].y += hv.x*w0.y + hv.y*w1.y + hv.z*w2.y + hv.w*w3.y;
            acc[i].z += hv.x*w0.z + hv.y*w1.z + hv.z*w2.z + hv.w*w3.z;
            acc[i].w += hv.x*w0.w + hv.y*w1.w + hv.z*w2.w + hv.w*w3.w;
        }
    }
#pragma unroll
    for (int i = 0; i < 2; ++i)
        if (val[i]) ((float4*)m1)[(node0 + i) * 4 + jq] = acc[i];
}

// kC3: dis = rsqrt(1+deg) (grid covers n) + scatter edges into final CSR.
// csr entry: low16 = src node id, high16 = fp16 weight.
__global__ void kC3(const int* __restrict__ row, const int* __restrict__ col,
                    const float* __restrict__ ew,
                    const unsigned long long* __restrict__ cd,
                    int* __restrict__ cur, unsigned int* __restrict__ csr,
                    float* __restrict__ dis, int e, int n) {
    int tid = threadIdx.x;
    int gi = blockIdx.x * 256 + tid;
    if (gi < n) {
        float deg = (float)(cd[gi] & ((1ull << 40) - 1)) * (1.f / 1048576.f);
        dis[gi] = rsqrtf(1.f + deg);
    }
    int start = blockIdx.x * ASLICE;
    int end = min(start + ASLICE, e);
    for (int i = start + tid; i < end; i += 256) {
        int p = atomicAdd(&cur[col[i]], 1);
        csr[p] = (unsigned)row[i] | ((unsigned)f2h(ew[i]) << 16);
    }
}

// ---------------- L1 gather: EPI (bias+relu+stats) + CSR rescale write-back ----------------
__global__ void k_l1gather(const float* __restrict__ src, const int* __restrict__ ptr,
                           unsigned int* __restrict__ csr, const float* __restrict__ dis,
                           const float* __restrict__ bias, double* __restrict__ partOut,
                           float* __restrict__ out, int n) {
    __shared__ float ls[16], lq[16];
    int tid = threadIdx.x;
    if (tid < 16) { ls[tid] = 0.f; lq[tid] = 0.f; }
    __syncthreads();
    int t = blockIdx.x * 256 + tid;
    int node = t >> 2;
    int l4 = t & 3;
    bool valid = node < n;
    int nc = valid ? node : n - 1;
    const float4* s4 = (const float4*)src;
    float dc = dis[nc];
    float w0 = dc * dc;
    float4 v = s4[nc * 4 + l4];
    float4 acc = { w0 * v.x, w0 * v.y, w0 * v.z, w0 * v.w };
    int p0 = ptr[nc], p1 = ptr[nc + 1];
    int p = p0;
    for (; p + 4 <= p1; p += 4) {
        unsigned int c0 = csr[p], c1 = csr[p+1], c2 = csr[p+2], c3 = csr[p+3];
        int s0i = c0 & 0xFFFF, s1i = c1 & 0xFFFF, s2i = c2 & 0xFFFF, s3i = c3 & 0xFFFF;
        float e0 = dis[s0i] * h2f((unsigned short)(c0 >> 16)) * dc;
        float e1 = dis[s1i] * h2f((unsigned short)(c1 >> 16)) * dc;
        float e2 = dis[s2i] * h2f((unsigned short)(c2 >> 16)) * dc;
        float e3 = dis[s3i] * h2f((unsigned short)(c3 >> 16)) * dc;
        float4 u0 = s4[s0i * 4 + l4];
        float4 u1 = s4[s1i * 4 + l4];
        float4 u2 = s4[s2i * 4 + l4];
        float4 u3 = s4[s3i * 4 + l4];
        acc.x += e0*u0.x + e1*u1.x + e2*u2.x + e3*u3.x;
        acc.y += e0*u0.y + e1*u1.y + e2*u2.y + e3*u3.y;
        acc.z += e0*u0.z + e1*u1.z + e2*u2.z + e3*u3.z;
        acc.w += e0*u0.w + e1*u1.w + e2*u2.w + e3*u3.w;
        if (l4 == 0) {
            csr[p]   = (unsigned)s0i | ((unsigned)f2h(e0) << 16);
            csr[p+1] = (unsigned)s1i | ((unsigned)f2h(e1) << 16);
            csr[p+2] = (unsigned)s2i | ((unsigned)f2h(e2) << 16);
            csr[p+3] = (unsigned)s3i | ((unsigned)f2h(e3) << 16);
        }
    }
    for (; p < p1; ++p) {
        unsigned int ce = csr[p];
        int si = ce & 0xFFFF;
        float w = dis[si] * h2f((unsigned short)(ce >> 16)) * dc;
        float4 u = s4[si * 4 + l4];
        acc.x += w*u.x; acc.y += w*u.y; acc.z += w*u.z; acc.w += w*u.w;
        if (l4 == 0) csr[p] = (unsigned)si | ((unsigned)f2h(w) << 16);
    }
    float4 b = ((const float4*)bias)[l4];
    acc.x = fmaxf(acc.x + b.x, 0.f);
    acc.y = fmaxf(acc.y + b.y, 0.f);
    acc.z = fmaxf(acc.z + b.z, 0.f);
    acc.w = fmaxf(acc.w + b.w, 0.f);
    if (valid) ((float4*)out)[nc * 4 + l4] = acc;
    float s0 = valid ? acc.x : 0.f, s1 = valid ? acc.y : 0.f;
    float s2 = valid ? acc.z : 0.f, s3 = valid ? acc.w : 0.f;
    float q0 = s0*s0, q1 = s1*s1, q2 = s2*s2, q3 = s3*s3;
    for (int off = 4; off < 64; off <<= 1) {
        s0 += __shfl_down(s0, off, 64); s1 += __shfl_down(s1, off, 64);
        s2 += __shfl_down(s2, off, 64); s3 += __shfl_down(s3, off, 64);
        q0 += __shfl_down(q0, off, 64); q1 += __shfl_down(q1, off, 64);
        q2 += __shfl_down(q2, off, 64); q3 += __shfl_down(q3, off, 64);
    }
    int lane = tid & 63;
    if (lane < 4) {
        atomicAdd(&ls[4*lane+0], s0); atomicAdd(&ls[4*lane+1], s1);
        atomicAdd(&ls[4*lane+2], s2); atomicAdd(&ls[4*lane+3], s3);
        atomicAdd(&lq[4*lane+0], q0); atomicAdd(&lq[4*lane+1], q1);
        atomicAdd(&lq[4*lane+2], q2); atomicAdd(&lq[4*lane+3], q3);
    }
    __syncthreads();
    int bkt = (blockIdx.x & (NBUCKET - 1)) * 256;
    if (tid < 16) {
        atomicAdd(&partOut[bkt + tid], (double)ls[tid]);
        atomicAdd(&partOut[bkt + 128 + tid], (double)lq[tid]);
    }
}

// row loader: fp32 float4 or fp16 ushort4 -> float4
template <int D, int F16>
__device__ __forceinline__ float4 load_row(const void* src, int node, int l4) {
    if (F16) {
        const unsigned short* sb = (const unsigned short*)src;
        ushort4 r = *(const ushort4*)(sb + (size_t)node * D + (l4 << 2));
        float4 f;
        f.x = h2f(r.x); f.y = h2f(r.y); f.z = h2f(r.z); f.w = h2f(r.w);
        return f;
    } else {
        const float4* s4 = (const float4*)src;
        return s4[(size_t)node * (D / 4) + l4];
    }
}

// 16B-wide fp16 row loader: 8 fp16 per lane
template <int D>
__device__ __forceinline__ void ldrow16(const unsigned short* __restrict__ src, int node, int l8,
                                        float4& a, float4& b) {
    uint4 r = *(const uint4*)(src + (size_t)node * D + (l8 << 3));
    a.x = h2f((unsigned short)(r.x)); a.y = h2f((unsigned short)(r.x >> 16));
    a.z = h2f((unsigned short)(r.y)); a.w = h2f((unsigned short)(r.y >> 16));
    b.x = h2f((unsigned short)(r.z)); b.y = h2f((unsigned short)(r.z >> 16));
    b.z = h2f((unsigned short)(r.w)); b.w = h2f((unsigned short)(r.w >> 16));
}

// ---------------- fused layer (F2 only — 2KB Wl): gather -> LDS rows -> gemm ------------
template <int DIN, int DOUT, int EP, int POSTAFF, int PREAFF, int RELU,
          int F16IN, int F16OUT, int NPB>
__global__ void __launch_bounds__(256) k_fused(
        const void* __restrict__ src, const int* __restrict__ ptr,
        const unsigned int* __restrict__ csr, const float* __restrict__ dis,
        const double* __restrict__ partIn, const float* __restrict__ gmv,
        const float* __restrict__ btv, const float* __restrict__ W,
        const float* __restrict__ bias, double* __restrict__ partOut,
        void* __restrict__ out, int n) {
    const int TPN1 = DIN / 4, LPN = TPN1 * EP, GN1 = 256 / LPN;
    const int TPN2 = DOUT / 4, G2 = 256 / TPN2;
    const int HS = DIN + 4;
    __shared__ float Wl[DIN * DOUT];
    __shared__ float hrow[NPB * HS];
    __shared__ float scs[DIN], shs[DIN];
    __shared__ float ls[DOUT], lq[DOUT];
    int tid = threadIdx.x;
    for (int i = tid; i < DIN * DOUT / 4; i += 256)
        ((float4*)Wl)[i] = ((const float4*)W)[i];
    if (tid < DIN) bn_coef(partIn, gmv, btv, tid, n, scs, shs);
    if (tid < DOUT) { ls[tid] = 0.f; lq[tid] = 0.f; }
    __syncthreads();

    int nodebase = blockIdx.x * NPB;
    {
        int grp = tid / LPN, r = tid % LPN;
        int e0 = r / TPN1, l4 = r % TPN1;
        float4 sc = ((const float4*)scs)[l4];
        float4 sh = ((const float4*)shs)[l4];
#pragma unroll
        for (int pass = 0; pass < NPB / GN1; ++pass) {
            int nl = pass * GN1 + grp;
            int node = nodebase + nl;
            int nc = node < n ? node : n - 1;
            float4 acc = {0.f, 0.f, 0.f, 0.f};
            float sumw = 0.f;
            if (e0 == 0) {
                float d = dis[nc];
                float w0 = d * d;
                float4 v = load_row<DIN, F16IN>(src, nc, l4);
                if (PREAFF) AFF4(v, sc, sh);
                acc.x = w0*v.x; acc.y = w0*v.y; acc.z = w0*v.z; acc.w = w0*v.w;
                sumw = w0;
            }
            int p0 = ptr[nc], p1 = ptr[nc + 1];
            int p = p0 + e0;
            for (; p + 3 * EP < p1; p += 4 * EP) {
                unsigned int c0 = csr[p], c1 = csr[p + EP], c2 = csr[p + 2*EP], c3 = csr[p + 3*EP];
                float e0w = h2f((unsigned short)(c0 >> 16)), e1w = h2f((unsigned short)(c1 >> 16));
                float e2w = h2f((unsigned short)(c2 >> 16)), e3w = h2f((unsigned short)(c3 >> 16));
                float4 u0 = load_row<DIN, F16IN>(src, c0 & 0xFFFF, l4);
                float4 u1 = load_row<DIN, F16IN>(src, c1 & 0xFFFF, l4);
                float4 u2 = load_row<DIN, F16IN>(src, c2 & 0xFFFF, l4);
                float4 u3 = load_row<DIN, F16IN>(src, c3 & 0xFFFF, l4);
                if (PREAFF) { AFF4(u0, sc, sh); AFF4(u1, sc, sh); AFF4(u2, sc, sh); AFF4(u3, sc, sh); }
                acc.x += e0w*u0.x + e1w*u1.x + e2w*u2.x + e3w*u3.x;
                acc.y += e0w*u0.y + e1w*u1.y + e2w*u2.y + e3w*u3.y;
                acc.z += e0w*u0.z + e1w*u1.z + e2w*u2.z + e3w*u3.z;
                acc.w += e0w*u0.w + e1w*u1.w + e2w*u2.w + e3w*u3.w;
                if (POSTAFF) sumw += e0w + e1w + e2w + e3w;
            }
            for (; p < p1; p += EP) {
                unsigned int ce = csr[p];
                float w = h2f((unsigned short)(ce >> 16));
                float4 u = load_row<DIN, F16IN>(src, ce & 0xFFFF, l4);
                if (PREAFF) AFF4(u, sc, sh);
                acc.x += w*u.x; acc.y += w*u.y; acc.z += w*u.z; acc.w += w*u.w;
                if (POSTAFF) sumw += w;
            }
#pragma unroll
            for (int off = TPN1; off < LPN; off <<= 1) {
                acc.x += __shfl_xor(acc.x, off, 64);
                acc.y += __shfl_xor(acc.y, off, 64);
                acc.z += __shfl_xor(acc.z, off, 64);
                acc.w += __shfl_xor(acc.w, off, 64);
                if (POSTAFF) sumw += __shfl_xor(sumw, off, 64);
            }
            if (POSTAFF) {
                acc.x = sc.x * acc.x + sh.x * sumw;
                acc.y = sc.y * acc.y + sh.y * sumw;
                acc.z = sc.z * acc.z + sh.z * sumw;
                acc.w = sc.w * acc.w + sh.w * sumw;
            }
            if (e0 == 0) *(float4*)&hrow[nl * HS + (l4 << 2)] = acc;
        }
    }
    __syncthreads();
    {
        int jq = tid % TPN2, g2 = tid / TPN2;
        float4 bv = ((const float4*)bias)[jq];
        float4 sv = {0,0,0,0}, qv = {0,0,0,0};
        for (int nl = g2; nl < NPB; nl += G2) {
            int node = nodebase + nl;
            bool valid = node < n;
            float4 a = {0.f, 0.f, 0.f, 0.f};
#pragma unroll
            for (int k4 = 0; k4 < DIN / 4; ++k4) {
                float4 hv = *(const float4*)&hrow[nl * HS + (k4 << 2)];
                const float* wb = &Wl[(k4 * 4) * DOUT + jq * 4];
                float4 w0 = *(const float4*)(wb);
                float4 w1 = *(const float4*)(wb + DOUT);
                float4 w2 = *(const float4*)(wb + 2 * DOUT);
                float4 w3 = *(const float4*)(wb + 3 * DOUT);
                a.x += hv.x*w0.x + hv.y*w1.x + hv.z*w2.x + hv.w*w3.x;
                a.y += hv.x*w0.y + hv.y*w1.y + hv.z*w2.y + hv.w*w3.y;
                a.z += hv.x*w0.z + hv.y*w1.z + hv.z*w2.z + hv.w*w3.z;
                a.w += hv.x*w0.w + hv.y*w1.w + hv.z*w2.w + hv.w*w3.w;
            }
            a.x += bv.x; a.y += bv.y; a.z += bv.z; a.w += bv.w;
            if (RELU) {
                a.x = fmaxf(a.x, 0.f); a.y = fmaxf(a.y, 0.f);
                a.z = fmaxf(a.z, 0.f); a.w = fmaxf(a.w, 0.f);
            }
            if (valid) {
                if (F16OUT) {
                    ushort4 o;
                    o.x = f2h(a.x); o.y = f2h(a.y); o.z = f2h(a.z); o.w = f2h(a.w);
                    *(ushort4*)((unsigned short*)out + (size_t)node * DOUT + (jq << 2)) = o;
                } else {
                    ((float4*)out)[(size_t)node * TPN2 + jq] = a;
                }
                sv.x += a.x; sv.y += a.y; sv.z += a.z; sv.w += a.w;
                qv.x += a.x*a.x; qv.y += a.y*a.y; qv.z += a.z*a.z; qv.w += a.w*a.w;
            }
        }
        for (int off = TPN2; off < 64; off <<= 1) {
            sv.x += __shfl_down(sv.x, off, 64); sv.y += __shfl_down(sv.y, off, 64);
            sv.z += __shfl_down(sv.z, off, 64); sv.w += __shfl_down(sv.w, off, 64);
            qv.x += __shfl_down(qv.x, off, 64); qv.y += __shfl_down(qv.y, off, 64);
            qv.z += __shfl_down(qv.z, off, 64); qv.w += __shfl_down(qv.w, off, 64);
        }
        int lane = tid & 63;
        if (lane < TPN2) {
            atomicAdd(&ls[4*lane+0], sv.x); atomicAdd(&ls[4*lane+1], sv.y);
            atomicAdd(&ls[4*lane+2], sv.z); atomicAdd(&ls[4*lane+3], sv.w);
            atomicAdd(&lq[4*lane+0], qv.x); atomicAdd(&lq[4*lane+1], qv.y);
            atomicAdd(&lq[4*lane+2], qv.z); atomicAdd(&lq[4*lane+3], qv.w);
        }
        __syncthreads();
        int bkt = (blockIdx.x & (NBUCKET - 1)) * 256;
        if (tid < DOUT) {
            atomicAdd(&partOut[bkt + tid], (double)ls[tid]);
            atomicAdd(&partOut[bkt + 128 + tid], (double)lq[tid]);
        }
    }
}

// ---------------- wide standalone gather (L3/L4/L5): 16B fp16 loads, EP=4, fp32-out -----
template <int D, int POSTAFF, int PREAFF>
__global__ void __launch_bounds__(256) k_wgather(
        const unsigned short* __restrict__ src, const int* __restrict__ ptr,
        const unsigned int* __restrict__ csr, const float* __restrict__ dis,
        const double* __restrict__ partIn, const float* __restrict__ gmv,
        const float* __restrict__ btv, float* __restrict__ out, int n) {
    const int RL = D / 8;          // lanes per 16B-row-chunk
    const int EP = 4;
    const int LPN = RL * EP;
    __shared__ float scs[D], shs[D];
    int tid = threadIdx.x;
    if (tid < D) bn_coef(partIn, gmv, btv, tid, n, scs, shs);
    __syncthreads();
    int t = blockIdx.x * 256 + tid;
    int node = t / LPN;
    int r = t - node * LPN;
    int e0 = r / RL;
    int l8 = r - e0 * RL;
    bool valid = node < n;
    int nc = valid ? node : n - 1;
    float4 scA = ((const float4*)scs)[l8 * 2],     shA = ((const float4*)shs)[l8 * 2];
    float4 scB = ((const float4*)scs)[l8 * 2 + 1], shB = ((const float4*)shs)[l8 * 2 + 1];
    float4 accA = {0.f,0.f,0.f,0.f}, accB = {0.f,0.f,0.f,0.f};
    float sumw = 0.f;
    if (e0 == 0) {
        float d = dis[nc];
        float w0 = d * d;
        float4 a, b2;
        ldrow16<D>(src, nc, l8, a, b2);
        if (PREAFF) { AFF4(a, scA, shA); AFF4(b2, scB, shB); }
        accA.x = w0*a.x;  accA.y = w0*a.y;  accA.z = w0*a.z;  accA.w = w0*a.w;
        accB.x = w0*b2.x; accB.y = w0*b2.y; accB.z = w0*b2.z; accB.w = w0*b2.w;
        sumw = w0;
    }
    int p0 = ptr[nc], p1 = ptr[nc + 1];
    int p = p0 + e0;
    for (; p + 3 * EP < p1; p += 4 * EP) {
        unsigned int c0 = csr[p], c1 = csr[p + EP], c2 = csr[p + 2*EP], c3 = csr[p + 3*EP];
        float w0 = h2f((unsigned short)(c0 >> 16)), w1 = h2f((unsigned short)(c1 >> 16));
        float w2 = h2f((unsigned short)(c2 >> 16)), w3 = h2f((unsigned short)(c3 >> 16));
        float4 a0, b0, a1, b1, a2, b2, a3, b3;
        ldrow16<D>(src, c0 & 0xFFFF, l8, a0, b0);
        ldrow16<D>(src, c1 & 0xFFFF, l8, a1, b1);
        ldrow16<D>(src, c2 & 0xFFFF, l8, a2, b2);
        ldrow16<D>(src, c3 & 0xFFFF, l8, a3, b3);
        if (PREAFF) {
            AFF4(a0, scA, shA); AFF4(b0, scB, shB);
            AFF4(a1, scA, shA); AFF4(b1, scB, shB);
            AFF4(a2, scA, shA); AFF4(b2, scB, shB);
            AFF4(a3, scA, shA); AFF4(b3, scB, shB);
        }
        accA.x += w0*a0.x + w1*a1.x + w2*a2.x + w3*a3.x;
        accA.y += w0*a0.y + w1*a1.y + w2*a2.y + w3*a3.y;
        accA.z += w0*a0.z + w1*a1.z + w2*a2.z + w3*a3.z;
        accA.w += w0*a0.w + w1*a1.w + w2*a2.w + w3*a3.w;
        accB.x += w0*b0.x + w1*b1.x + w2*b2.x + w3*b3.x;
        accB.y += w0*b0.y + w1*b1.y + w2*b2.y + w3*b3.y;
        accB.z += w0*b0.z + w1*b1.z + w2*b2.z + w3*b3.z;
        accB.w += w0*b0.w + w1*b1.w + w2*b2.w + w3*b3.w;
        if (POSTAFF) sumw += w0 + w1 + w2 + w3;
    }
    for (; p < p1; p += EP) {
        unsigned int ce = csr[p];
        float w = h2f((unsigned short)(ce >> 16));
        float4 a, b2;
        ldrow16<D>(src, ce & 0xFFFF, l8, a, b2);
        if (PREAFF) { AFF4(a, scA, shA); AFF4(b2, scB, shB); }
        accA.x += w*a.x;  accA.y += w*a.y;  accA.z += w*a.z;  accA.w += w*a.w;
        accB.x += w*b2.x; accB.y += w*b2.y; accB.z += w*b2.z; accB.w += w*b2.w;
        if (POSTAFF) sumw += w;
    }
#pragma unroll
    for (int off = RL; off < LPN; off <<= 1) {
        accA.x += __shfl_xor(accA.x, off, 64); accA.y += __shfl_xor(accA.y, off, 64);
        accA.z += __shfl_xor(accA.z, off, 64); accA.w += __shfl_xor(accA.w, off, 64);
        accB.x += __shfl_xor(accB.x, off, 64); accB.y += __shfl_xor(accB.y, off, 64);
        accB.z += __shfl_xor(accB.z, off, 64); accB.w += __shfl_xor(accB.w, off, 64);
        if (POSTAFF) sumw += __shfl_xor(sumw, off, 64);
    }
    if (POSTAFF) {
        accA.x = scA.x * accA.x + shA.x * sumw; accA.y = scA.y * accA.y + shA.y * sumw;
        accA.z = scA.z * accA.z + shA.z * sumw; accA.w = scA.w * accA.w + shA.w * sumw;
        accB.x = scB.x * accB.x + shB.x * sumw; accB.y = scB.y * accB.y + shB.y * sumw;
        accB.z = scB.z * accB.z + shB.z * sumw; accB.w = scB.w * accB.w + shB.w * sumw;
    }
    if (valid && e0 == 0) {
        ((float4*)out)[(size_t)nc * (D / 4) + l8 * 2]     = accA;
        ((float4*)out)[(size_t)nc * (D / 4) + l8 * 2 + 1] = accB;
    }
}

// ---------------- standalone gemm DIN -> DOUT, bias + optional relu + stats --------------
// POOL=1: don't materialize output; accumulate group sums (double) into pooled[NG][DOUT]
// via LDS per-block aggregation (batch is sorted; a 32-node block spans ~1-2 groups).
template <int DIN, int DOUT, int RELU, int F16OUT, int POOL>
__global__ void k_sgemm(const float* __restrict__ h, const float* __restrict__ W,
                        const float* __restrict__ bias, double* __restrict__ partOut,
                        void* __restrict__ m, const int* __restrict__ batch,
                        double* __restrict__ pooled, int n) {
    const int TPN = DOUT / 4, GPB = 256 / TPN, NPT = 4;
    const int NPBLK = GPB * NPT;
    const int MAXG = 34;
    __shared__ float Wl[DIN * DOUT];
    __shared__ float ls[DOUT], lq[DOUT];
    __shared__ double pool_l[POOL ? MAXG * DOUT : 1];
    __shared__ int gmaxs;
    int tid = threadIdx.x;
    for (int i = tid; i < DIN * DOUT / 4; i += 256)
        ((float4*)Wl)[i] = ((const float4*)W)[i];
    if (tid < DOUT) { ls[tid] = 0.f; lq[tid] = 0.f; }
    int gbase = 0;
    if (POOL) {
        for (int i = tid; i < MAXG * DOUT; i += 256) pool_l[i] = 0.;
        if (tid == 0) gmaxs = 0;
        int bn0 = blockIdx.x * NPBLK;
        gbase = batch[bn0 < n ? bn0 : n - 1];
    }
    __syncthreads();

    int jq = tid % TPN;
    int group = tid / TPN;
    int node0 = (blockIdx.x * GPB + group) * NPT;
    const float4* h4 = (const float4*)h;
    int hb[NPT]; bool val[NPT];
#pragma unroll
    for (int i = 0; i < NPT; ++i) {
        int nd = node0 + i;
        val[i] = nd < n;
        hb[i] = (val[i] ? nd : n - 1) * (DIN / 4);
    }
    float4 acc[NPT];
#pragma unroll
    for (int i = 0; i < NPT; ++i) acc[i] = {0.f, 0.f, 0.f, 0.f};
#pragma unroll 4
    for (int k4 = 0; k4 < DIN / 4; ++k4) {
        const float* wb = &Wl[(k4 * 4) * DOUT + jq * 4];
        float4 w0 = *(const float4*)(wb);
        float4 w1 = *(const float4*)(wb + DOUT);
        float4 w2 = *(const float4*)(wb + 2 * DOUT);
        float4 w3 = *(const float4*)(wb + 3 * DOUT);
#pragma unroll
        for (int i = 0; i < NPT; ++i) {
            float4 hv = h4[hb[i] + k4];
            acc[i].x += hv.x*w0.x + hv.y*w1.x + hv.z*w2.x + hv.w*w3.x;
            acc[i].y += hv.x*w0.y + hv.y*w1.y + hv.z*w2.y + hv.w*w3.y;
            acc[i].z += hv.x*w0.z + hv.y*w1.z + hv.z*w2.z + hv.w*w3.z;
            acc[i].w += hv.x*w0.w + hv.y*w1.w + hv.z*w2.w + hv.w*w3.w;
        }
    }
    float4 bv = ((const float4*)bias)[jq];
    float4 sv = {0,0,0,0}, qv = {0,0,0,0};
#pragma unroll
    for (int i = 0; i < NPT; ++i) {
        float4 a = acc[i];
        a.x += bv.x; a.y += bv.y; a.z += bv.z; a.w += bv.w;
        if (RELU) {
            a.x = fmaxf(a.x, 0.f); a.y = fmaxf(a.y, 0.f);
            a.z = fmaxf(a.z, 0.f); a.w = fmaxf(a.w, 0.f);
        }
        if (val[i]) {
            if (POOL) {
                int off = batch[node0 + i] - gbase;
                if (off < MAXG) {
                    atomicAdd(&pool_l[off * DOUT + jq * 4 + 0], (double)a.x);
                    atomicAdd(&pool_l[off * DOUT + jq * 4 + 1], (double)a.y);
                    atomicAdd(&pool_l[off * DOUT + jq * 4 + 2], (double)a.z);
                    atomicAdd(&pool_l[off * DOUT + jq * 4 + 3], (double)a.w);
                    if (jq == 0) atomicMax(&gmaxs, off);
                } else {
                    double* pg = &pooled[(size_t)(gbase + off) * DOUT + jq * 4];
                    atomicAdd(pg + 0, (double)a.x); atomicAdd(pg + 1, (double)a.y);
                    atomicAdd(pg + 2, (double)a.z); atomicAdd(pg + 3, (double)a.w);
                }
            } else {
                if (F16OUT) {
                    ushort4 o;
                    o.x = f2h(a.x); o.y = f2h(a.y); o.z = f2h(a.z); o.w = f2h(a.w);
                    *(ushort4*)((unsigned short*)m + (size_t)(node0 + i) * DOUT + (jq << 2)) = o;
                } else {
                    ((float4*)m)[(size_t)(node0 + i) * TPN + jq] = a;
                }
            }
            sv.x += a.x; sv.y += a.y; sv.z += a.z; sv.w += a.w;
            qv.x += a.x*a.x; qv.y += a.y*a.y; qv.z += a.z*a.z; qv.w += a.w*a.w;
        }
    }
    for (int off = TPN; off < 64; off <<= 1) {
        sv.x += __shfl_down(sv.x, off, 64); sv.y += __shfl_down(sv.y, off, 64);
        sv.z += __shfl_down(sv.z, off, 64); sv.w += __shfl_down(sv.w, off, 64);
        qv.x += __shfl_down(qv.x, off, 64); qv.y += __shfl_down(qv.y, off, 64);
        qv.z += __shfl_down(qv.z, off, 64); qv.w += __shfl_down(qv.w, off, 64);
    }
    int lane = tid & 63;
    if (lane < TPN) {
        atomicAdd(&ls[4*lane+0], sv.x); atomicAdd(&ls[4*lane+1], sv.y);
        atomicAdd(&ls[4*lane+2], sv.z); atomicAdd(&ls[4*lane+3], sv.w);
        atomicAdd(&lq[4*lane+0], qv.x); atomicAdd(&lq[4*lane+1], qv.y);
        atomicAdd(&lq[4*lane+2], qv.z); atomicAdd(&lq[4*lane+3], qv.w);
    }
    __syncthreads();
    int bkt = (blockIdx.x & (NBUCKET - 1)) * 256;
    if (tid < DOUT) {
        atomicAdd(&partOut[bkt + tid], (double)ls[tid]);
        atomicAdd(&partOut[bkt + 128 + tid], (double)lq[tid]);
    }
    if (POOL) {
        int gm = gmaxs;
        for (int i = tid; i < (gm + 1) * DOUT; i += 256) {
            double v = pool_l[i];
            if (v != 0.) atomicAdd(&pooled[(size_t)gbase * DOUT + i], v);
        }
    }
}

// ---------------- pool head: BN5(from stats) applied to pooled sums + MLP ----------------
__global__ void __launch_bounds__(128) k_poolhead(
        const double* __restrict__ pooled, const int* __restrict__ batch,
        const double* __restrict__ partIn, const float* __restrict__ gmv,
        const float* __restrict__ btv,
        const float* __restrict__ fc1w, const float* __restrict__ fc1b,
        const float* __restrict__ fc2w, const float* __restrict__ fc2b,
        float* __restrict__ out, int n) {
    __shared__ float pl[128];
    __shared__ float scs[128], shs[128];
    int g = blockIdx.x;
    int tid = threadIdx.x;
    bn_coef(partIn, gmv, btv, tid, n, scs, shs);
    int a = 0, b = n;
    while (a < b) { int mid = (a + b) >> 1; if (batch[mid] < g) a = mid + 1; else b = mid; }
    int lo = a;
    b = n;
    while (a < b) { int mid = (a + b) >> 1; if (batch[mid] < g + 1) a = mid + 1; else b = mid; }
    int hi = a;
    float cntf = (float)(hi - lo);
    float p = scs[tid] * (float)pooled[g * 128 + tid] + shs[tid] * cntf;
    pl[tid] = fmaxf(p, 0.f);
    __syncthreads();
    if (tid < 64) {
        float v1 = fc1b[tid];
        for (int k = 0; k < 128; ++k) v1 += pl[k] * fc1w[k * 64 + tid];
        v1 = fmaxf(v1, 0.f);
        float v = v1 * fc2w[tid];
        for (int off = 32; off > 0; off >>= 1) v += __shfl_down(v, off, 64);
        if (tid == 0) out[g] = v + fc2b[0];
    }
}

// ---------------- driver ----------------
extern "C" void kernel_launch(void* const* d_in, const int* in_sizes, int n_in,
                              void* d_out, int out_size, void* d_ws, size_t ws_size,
                              hipStream_t stream) {
    const float* x     = (const float*)d_in[0];
    const int*   ei    = (const int*)d_in[1];
    const float* ew    = (const float*)d_in[2];
    const int*   batch = (const int*)d_in[3];
    const float *W[5], *b[5], *gm[5], *bt[5];
    for (int i = 0; i < 5; ++i) {
        W[i]  = (const float*)d_in[4 + 4 * i];
        b[i]  = (const float*)d_in[5 + 4 * i];
        gm[i] = (const float*)d_in[6 + 4 * i];
        bt[i] = (const float*)d_in[7 + 4 * i];
    }
    const float* fc1w = (const float*)d_in[24];
    const float* fc1b = (const float*)d_in[25];
    const float* fc2w = (const float*)d_in[26];
    const float* fc2b = (const float*)d_in[27];
    float* out = (float*)d_out;

    // workspace layout
    char* wsb = (char*)d_ws;
    float* dis    = (float*)wsb;  wsb += sizeof(float) * NN;
    int*   ptr    = (int*)wsb;    wsb += sizeof(int) * (NN + 4);
    int*   cur    = (int*)wsb;    wsb += sizeof(int) * NN;
    unsigned long long* cd = (unsigned long long*)wsb; wsb += sizeof(unsigned long long) * NN;
    double* part   = (double*)wsb;  wsb += sizeof(double) * 5 * PARTSZ;
    double* pooled = (double*)wsb;  wsb += sizeof(double) * NG * 128;
    unsigned int* csru = (unsigned int*)wsb; wsb += sizeof(unsigned int) * NE;
    unsigned short* bufB1 = (unsigned short*)wsb;  wsb += sizeof(unsigned short) * (size_t)NN * 64;
    unsigned short* bufB2 = (unsigned short*)wsb;  wsb += sizeof(unsigned short) * (size_t)NN * 64;
    float* buf1   = (float*)wsb;  wsb += sizeof(float) * (size_t)NN * 64;    // gathers / m1
    float* buf2   = (float*)wsb;  wsb += sizeof(float) * (size_t)NN * 16;    // L1 out

    const int* row = ei;
    const int* col = ei + NE;
    const int B = 256;
    const int NBF = (NN + 15) / 16;       // fused F2 blocks
    const int GB1 = (NN + 511) / 512;     // gemm1 blocks (1024-thread, 512 nodes/blk)
    const int ZN = 5 * PARTSZ + NG * 128; // part+pooled zero region (contiguous doubles)

    // prologue: zero count/deg; count+deg (1 u64 atomic/edge) + zero part/pooled;
    // scan (block 0) overlapped with gemm1; dis + direct CSR scatter.
    hipMemsetAsync(cd, 0, sizeof(unsigned long long) * NN, stream);
    kC1<<<ABLK, B, 0, stream>>>(col, ew, cd, part, ZN, NE);
    kC2g<<<1 + GB1, 1024, 0, stream>>>(cd, ptr, cur, x, W[0], buf1, NN);
    kC3<<<ABLK, B, 0, stream>>>(row, col, ew, cd, cur, csru, dis, NE, NN);

    // L1 gather: bias+relu+stats (+ CSR rescale write-back, packed u16|f16)
    k_l1gather<<<(NN * 4 + 255) / 256, B, 0, stream>>>(buf1, ptr, csru, dis,
                                                       b[0], part + 0 * PARTSZ, buf2, NN);

    // F2: 16->32 fused (2KB Wl), consume part[0], fp32 in, fp16 out
    k_fused<16, 32, 4, 1, 0, 1, 0, 1, 16><<<NBF, B, 0, stream>>>(
        buf2, ptr, csru, dis, part + 0 * PARTSZ, gm[0], bt[0],
        W[1], b[1], part + 1 * PARTSZ, bufB1, NN);

    // L3: wide gather32 (BN2 hoisted) then gemm 32->64
    k_wgather<32, 1, 0><<<(int)(((long)NN * 16 + 255) / 256), B, 0, stream>>>(
        bufB1, ptr, csru, dis, part + 1 * PARTSZ, gm[1], bt[1], buf1, NN);
    k_sgemm<32, 64, 1, 1, 0><<<(NN + 63) / 64, B, 0, stream>>>(
        buf1, W[2], b[2], part + 2 * PARTSZ, bufB2, nullptr, nullptr, NN);

    // L4: wide gather64 (BN3 hoisted) then gemm 64->64
    k_wgather<64, 1, 0><<<(int)(((long)NN * 32 + 255) / 256), B, 0, stream>>>(
        bufB2, ptr, csru, dis, part + 2 * PARTSZ, gm[2], bt[2], buf1, NN);
    k_sgemm<64, 64, 0, 1, 0><<<(NN + 63) / 64, B, 0, stream>>>(
        buf1, W[3], b[3], part + 3 * PARTSZ, bufB1, nullptr, nullptr, NN);

    // L5: wide gather64 (per-edge relu(BN4)) then gemm 64->128 fused with pool (f64 sums)
    k_wgather<64, 0, 1><<<(int)(((long)NN * 32 + 255) / 256), B, 0, stream>>>(
        bufB1, ptr, csru, dis, part + 3 * PARTSZ, gm[3], bt[3], buf1, NN);
    k_sgemm<64, 128, 0, 0, 1><<<(NN + 31) / 32, B, 0, stream>>>(
        buf1, W[4], b[4], part + 4 * PARTSZ, nullptr, batch, pooled, NN);

    // head: BN5 (stats from part[4]) on pooled sums + MLP
    k_poolhead<<<NG, 128, 0, stream>>>(pooled, batch, part + 4 * PARTSZ, gm[4], bt[4],
                                       fc1w, fc1b, fc2w, fc2b, out, NN);
}

// Round 6
// 382.626 us; speedup vs baseline: 1.1135x; 1.1135x over previous
//
#include <hip/hip_runtime.h>
#include <stdint.h>

#define NN 50000
#define NE 800000
#define NG 256
#define NBUCKET 16
#define PARTSZ (NBUCKET * 256)

// bucketed CSR build params
#define NBKT 391      // node buckets of 128
#define ABLK 391
#define ASLICE 2048
#define BCAP 2560

#define AFF4(u, sc, sh) { u.x = fmaxf(sc.x*u.x+sh.x,0.f); u.y = fmaxf(sc.y*u.y+sh.y,0.f); \
                          u.z = fmaxf(sc.z*u.z+sh.z,0.f); u.w = fmaxf(sc.w*u.w+sh.w,0.f); }

// BN coefficients from double-precision partial sums (replay-stable)
__device__ __forceinline__ void bn_coef(const double* __restrict__ partIn,
                                        const float* __restrict__ gmv,
                                        const float* __restrict__ btv,
                                        int tid, int n, float* scs, float* shs) {
    double s = 0., q = 0.;
#pragma unroll
    for (int b2 = 0; b2 < NBUCKET; ++b2) {
        s += partIn[b2 * 256 + tid];
        q += partIn[b2 * 256 + 128 + tid];
    }
    double mu = s / (double)n;
    double var = q / (double)n - mu * mu;
    float a = gmv[tid] * rsqrtf((float)var + 1e-5f);
    scs[tid] = a;
    shs[tid] = btv[tid] - (float)mu * a;
}

// wave-parallel exclusive scan of totals[0..NBKT) into sbase[0..NBKT] (sbase[NBKT]=sum)
__device__ __forceinline__ void scan_totals(const int* __restrict__ totals,
                                            int* __restrict__ sbase, int tid) {
    if (tid < 64) {
        const int C = (NBKT + 63) / 64;  // 7
        int tv[C];
        int s = 0;
        int i0 = tid * C;
#pragma unroll
        for (int j = 0; j < C; ++j) {
            int idx = i0 + j;
            int x = (idx < NBKT) ? totals[idx] : 0;
            tv[j] = x; s += x;
        }
        int inc = s;
        for (int off = 1; off < 64; off <<= 1) {
            int t2 = __shfl_up(inc, off, 64);
            if (tid >= off) inc += t2;
        }
        int run = inc - s;
#pragma unroll
        for (int j = 0; j < C; ++j) {
            int idx = i0 + j;
            if (idx < NBKT) sbase[idx] = run;
            run += tv[j];
        }
        if (tid == 63) sbase[NBKT] = run;
    }
}

// ---------------- prologue ----------------
__global__ void kA1(const int* __restrict__ col, int* __restrict__ bb,
                    double* __restrict__ zz, int zn, int e) {
    __shared__ int cnt[NBKT];
    for (int j = threadIdx.x; j < NBKT; j += 256) cnt[j] = 0;
    for (int i = blockIdx.x * 256 + threadIdx.x; i < zn; i += ABLK * 256) zz[i] = 0.;
    __syncthreads();
    int start = blockIdx.x * ASLICE;
    int end = min(start + ASLICE, e);
    for (int i = start + threadIdx.x; i < end; i += 256)
        atomicAdd(&cnt[col[i] >> 7], 1);
    __syncthreads();
    for (int j = threadIdx.x; j < NBKT; j += 256) bb[blockIdx.x * NBKT + j] = cnt[j];
}

__global__ void kA2a(int* __restrict__ bb, int* __restrict__ totals) {
    __shared__ int v[ABLK];
    int k = blockIdx.x;
    int tid = threadIdx.x;
    for (int b = tid; b < ABLK; b += 256) v[b] = bb[b * NBKT + k];
    __syncthreads();
    if (tid < 64) {
        const int C = (ABLK + 63) / 64;  // 7
        int tv[C];
        int s = 0;
        int i0 = tid * C;
#pragma unroll
        for (int j = 0; j < C; ++j) {
            int idx = i0 + j;
            int x = (idx < ABLK) ? v[idx] : 0;
            tv[j] = x; s += x;
        }
        int inc = s;
        for (int off = 1; off < 64; off <<= 1) {
            int t2 = __shfl_up(inc, off, 64);
            if (tid >= off) inc += t2;
        }
        int run = inc - s;
#pragma unroll
        for (int j = 0; j < C; ++j) {
            int idx = i0 + j;
            if (idx < ABLK) v[idx] = run;
            run += tv[j];
        }
        if (tid == 63) totals[k] = run;
    }
    __syncthreads();
    for (int b = tid; b < ABLK; b += 256) bb[b * NBKT + k] = v[b];
}

// A3 (blocks [0,ABLK)) + independent L1 gemm 128->16 (blocks [ABLK,..)) in one dispatch
__global__ void kA3g(const int* __restrict__ row, const int* __restrict__ col,
                     const float* __restrict__ ew, const int* __restrict__ bb,
                     const int* __restrict__ totals, int2* __restrict__ staging,
                     const float* __restrict__ x, const float* __restrict__ W0,
                     float* __restrict__ m1, int e, int n) {
    __shared__ int cur[NBKT];
    __shared__ int sbase[NBKT + 1];
    __shared__ float Wl[128 * 16];
    int tid = threadIdx.x;
    if ((int)blockIdx.x < ABLK) {
        scan_totals(totals, sbase, tid);
        __syncthreads();
        for (int j = tid; j < NBKT; j += 256)
            cur[j] = sbase[j] + bb[blockIdx.x * NBKT + j];
        __syncthreads();
        int start = blockIdx.x * ASLICE;
        int end = min(start + ASLICE, e);
        for (int i = start + tid; i < end; i += 256) {
            int c = col[i];
            int p = atomicAdd(&cur[c >> 7], 1);
            staging[p] = make_int2(row[i] | ((c & 127) << 16), __float_as_int(ew[i]));
        }
        return;
    }
    int bid = (int)blockIdx.x - ABLK;
    for (int i = tid; i < 128 * 16 / 4; i += 256)
        ((float4*)Wl)[i] = ((const float4*)W0)[i];
    __syncthreads();
    int jq = tid % 4, group = tid / 4;
    int node0 = (bid * 64 + group) * 2;
    const float4* h4 = (const float4*)x;
    int hb[2]; bool val[2];
#pragma unroll
    for (int i = 0; i < 2; ++i) {
        int nd = node0 + i;
        val[i] = nd < n;
        hb[i] = (val[i] ? nd : n - 1) * 32;
    }
    float4 acc[2];
    acc[0] = {0,0,0,0}; acc[1] = {0,0,0,0};
#pragma unroll 4
    for (int k4 = 0; k4 < 32; ++k4) {
        const float* wb = &Wl[(k4 * 4) * 16 + jq * 4];
        float4 w0 = *(const float4*)(wb);
        float4 w1 = *(const float4*)(wb + 16);
        float4 w2 = *(const float4*)(wb + 32);
        float4 w3 = *(const float4*)(wb + 48);
#pragma unroll
        for (int i = 0; i < 2; ++i) {
            float4 hv = h4[hb[i] + k4];
            acc[i].x += hv.x*w0.x + hv.y*w1.x + hv.z*w2.x + hv.w*w3.x;
            acc[i].y += hv.x*w0.y + hv.y*w1.y + hv.z*w2.y + hv.w*w3.y;
            acc[i].z += hv.x*w0.z + hv.y*w1.z + hv.z*w2.z + hv.w*w3.z;
            acc[i].w += hv.x*w0.w + hv.y*w1.w + hv.z*w2.w + hv.w*w3.w;
        }
    }
#pragma unroll
    for (int i = 0; i < 2; ++i)
        if (val[i]) ((float4*)m1)[(node0 + i) * 4 + jq] = acc[i];
}

// csr entry: .x = src node id, .y = fp32 weight bits; degree summed in f64 (order-robust)
__global__ void __launch_bounds__(256) kB(const int* __restrict__ totals,
                                          const int2* __restrict__ staging,
                                          int2* __restrict__ csr, int* __restrict__ ptr,
                                          float* __restrict__ dis, int n) {
    __shared__ int2 st[BCAP];
    __shared__ int2 outb[BCAP];
    __shared__ int hist[129];
    __shared__ int cur[128];
    __shared__ int sbase[NBKT + 1];
    int k = blockIdx.x, t = threadIdx.x;
    scan_totals(totals, sbase, t);
    if (t < 129) hist[t] = 0;
    __syncthreads();
    int base = sbase[k], cnt = sbase[k + 1] - sbase[k];
    int node0 = k << 7;
    int ncov = min(128, n - node0);
    if (cnt <= BCAP) {
        for (int i = t; i < cnt; i += 256) {
            int2 v = staging[base + i];
            st[i] = v;
            atomicAdd(&hist[v.x >> 16], 1);
        }
        __syncthreads();
        if (t == 0) {
            int run = 0;
            for (int j = 0; j < 128; ++j) { int h = hist[j]; hist[j] = run; run += h; }
            hist[128] = run;
        }
        __syncthreads();
        if (t < 128) cur[t] = hist[t];
        if (t < ncov) ptr[node0 + t] = base + hist[t];
        __syncthreads();
        for (int i = t; i < cnt; i += 256) {
            int2 v = st[i];
            int j = v.x >> 16;
            int p = atomicAdd(&cur[j], 1);
            outb[p] = make_int2(v.x & 0xFFFF, v.y);
        }
        __syncthreads();
        for (int i = t; i < cnt; i += 256) csr[base + i] = outb[i];
        if (t < ncov) {
            double s = 1.;
            int a = hist[t], b2 = hist[t + 1];
            for (int p = a; p < b2; ++p) s += (double)__int_as_float(outb[p].y);
            dis[node0 + t] = rsqrtf((float)s);
        }
    } else {
        for (int i = t; i < cnt; i += 256) atomicAdd(&hist[staging[base + i].x >> 16], 1);
        __syncthreads();
        if (t == 0) {
            int run = 0;
            for (int j = 0; j < 128; ++j) { int h = hist[j]; hist[j] = run; run += h; }
            hist[128] = run;
        }
        __syncthreads();
        if (t < 128) cur[t] = hist[t];
        if (t < ncov) ptr[node0 + t] = base + hist[t];
        __syncthreads();
        for (int i = t; i < cnt; i += 256) {
            int2 v = staging[base + i];
            int j = v.x >> 16;
            int p = atomicAdd(&cur[j], 1);
            csr[base + p] = make_int2(v.x & 0xFFFF, v.y);
        }
        __threadfence_block();
        __syncthreads();
        if (t < ncov) {
            double s = 1.;
            int a = hist[t], b2 = hist[t + 1];
            for (int p = a; p < b2; ++p) s += (double)__int_as_float(csr[base + p].y);
            dis[node0 + t] = rsqrtf((float)s);
        }
    }
    if (k == gridDim.x - 1 && t == 0) ptr[n] = sbase[NBKT];
}

// ---------------- L1 gather: f64 acc, EPI (bias+relu+stats) + CSR rescale write-back -----
__global__ void k_l1gather(const float* __restrict__ src, const int* __restrict__ ptr,
                           int2* __restrict__ csr, const float* __restrict__ dis,
                           const float* __restrict__ bias, double* __restrict__ partOut,
                           float* __restrict__ out, int n) {
    int tid = threadIdx.x;
    int t = blockIdx.x * 256 + tid;
    int node = t >> 2;
    int l4 = t & 3;
    bool valid = node < n;
    int nc = valid ? node : n - 1;
    const float4* s4 = (const float4*)src;
    float dc = dis[nc];
    float w0 = dc * dc;
    float4 v = s4[nc * 4 + l4];
    double ax = (double)(w0 * v.x), ay = (double)(w0 * v.y);
    double az = (double)(w0 * v.z), aw = (double)(w0 * v.w);
    int p0 = ptr[nc], p1 = ptr[nc + 1];
    int p = p0;
    for (; p + 4 <= p1; p += 4) {
        int2 c0 = csr[p], c1 = csr[p+1], c2 = csr[p+2], c3 = csr[p+3];
        float e0 = dis[c0.x] * __int_as_float(c0.y) * dc;
        float e1 = dis[c1.x] * __int_as_float(c1.y) * dc;
        float e2 = dis[c2.x] * __int_as_float(c2.y) * dc;
        float e3 = dis[c3.x] * __int_as_float(c3.y) * dc;
        float4 u0 = s4[c0.x * 4 + l4];
        float4 u1 = s4[c1.x * 4 + l4];
        float4 u2 = s4[c2.x * 4 + l4];
        float4 u3 = s4[c3.x * 4 + l4];
        ax += (double)(e0*u0.x) + (double)(e1*u1.x) + (double)(e2*u2.x) + (double)(e3*u3.x);
        ay += (double)(e0*u0.y) + (double)(e1*u1.y) + (double)(e2*u2.y) + (double)(e3*u3.y);
        az += (double)(e0*u0.z) + (double)(e1*u1.z) + (double)(e2*u2.z) + (double)(e3*u3.z);
        aw += (double)(e0*u0.w) + (double)(e1*u1.w) + (double)(e2*u2.w) + (double)(e3*u3.w);
        if (l4 == 0) {
            csr[p]   = make_int2(c0.x, __float_as_int(e0));
            csr[p+1] = make_int2(c1.x, __float_as_int(e1));
            csr[p+2] = make_int2(c2.x, __float_as_int(e2));
            csr[p+3] = make_int2(c3.x, __float_as_int(e3));
        }
    }
    for (; p < p1; ++p) {
        int2 ce = csr[p];
        float w = dis[ce.x] * __int_as_float(ce.y) * dc;
        float4 u = s4[ce.x * 4 + l4];
        ax += (double)(w*u.x); ay += (double)(w*u.y);
        az += (double)(w*u.z); aw += (double)(w*u.w);
        if (l4 == 0) csr[p] = make_int2(ce.x, __float_as_int(w));
    }
    float4 b = ((const float4*)bias)[l4];
    float4 acc;
    acc.x = fmaxf((float)ax + b.x, 0.f);
    acc.y = fmaxf((float)ay + b.y, 0.f);
    acc.z = fmaxf((float)az + b.z, 0.f);
    acc.w = fmaxf((float)aw + b.w, 0.f);
    if (valid) ((float4*)out)[nc * 4 + l4] = acc;
    float s0 = valid ? acc.x : 0.f, s1 = valid ? acc.y : 0.f;
    float s2 = valid ? acc.z : 0.f, s3 = valid ? acc.w : 0.f;
    float q0 = s0*s0, q1 = s1*s1, q2 = s2*s2, q3 = s3*s3;
    for (int off = 4; off < 64; off <<= 1) {
        s0 += __shfl_down(s0, off, 64); s1 += __shfl_down(s1, off, 64);
        s2 += __shfl_down(s2, off, 64); s3 += __shfl_down(s3, off, 64);
        q0 += __shfl_down(q0, off, 64); q1 += __shfl_down(q1, off, 64);
        q2 += __shfl_down(q2, off, 64); q3 += __shfl_down(q3, off, 64);
    }
    int lane = tid & 63;
    int bkt = (blockIdx.x & (NBUCKET - 1)) * 256;
    if (lane < 4) {
        atomicAdd(&partOut[bkt + 4*lane + 0], (double)s0);
        atomicAdd(&partOut[bkt + 4*lane + 1], (double)s1);
        atomicAdd(&partOut[bkt + 4*lane + 2], (double)s2);
        atomicAdd(&partOut[bkt + 4*lane + 3], (double)s3);
        atomicAdd(&partOut[bkt + 128 + 4*lane + 0], (double)q0);
        atomicAdd(&partOut[bkt + 128 + 4*lane + 1], (double)q1);
        atomicAdd(&partOut[bkt + 128 + 4*lane + 2], (double)q2);
        atomicAdd(&partOut[bkt + 128 + 4*lane + 3], (double)q3);
    }
}

// ---------------- fused layer F2 (16->32): gather (f64 acc) -> LDS rows -> gemm ---------
template <int DIN, int DOUT, int EP, int POSTAFF, int RELU, int NPB>
__global__ void __launch_bounds__(256) k_fused(
        const float* __restrict__ src, const int* __restrict__ ptr,
        const int2* __restrict__ csr, const float* __restrict__ dis,
        const double* __restrict__ partIn, const float* __restrict__ gmv,
        const float* __restrict__ btv, const float* __restrict__ W,
        const float* __restrict__ bias, double* __restrict__ partOut,
        float* __restrict__ out, int n) {
    const int TPN1 = DIN / 4, LPN = TPN1 * EP, GN1 = 256 / LPN;
    const int TPN2 = DOUT / 4, G2 = 256 / TPN2;
    const int HS = DIN + 4;
    __shared__ float Wl[DIN * DOUT];
    __shared__ float hrow[NPB * HS];
    __shared__ float scs[DIN], shs[DIN];
    __shared__ double ls[DOUT], lq[DOUT];
    int tid = threadIdx.x;
    for (int i = tid; i < DIN * DOUT / 4; i += 256)
        ((float4*)Wl)[i] = ((const float4*)W)[i];
    if (tid < DIN) bn_coef(partIn, gmv, btv, tid, n, scs, shs);
    if (tid < DOUT) { ls[tid] = 0.; lq[tid] = 0.; }
    __syncthreads();

    int nodebase = blockIdx.x * NPB;
    {
        int grp = tid / LPN, r = tid % LPN;
        int e0 = r / TPN1, l4 = r % TPN1;
        float4 sc = ((const float4*)scs)[l4];
        float4 sh = ((const float4*)shs)[l4];
        const float4* s4 = (const float4*)src;
#pragma unroll
        for (int pass = 0; pass < NPB / GN1; ++pass) {
            int nl = pass * GN1 + grp;
            int node = nodebase + nl;
            int nc = node < n ? node : n - 1;
            double ax = 0., ay = 0., az = 0., aw = 0.;
            double sumw = 0.;
            if (e0 == 0) {
                float d = dis[nc];
                float w0 = d * d;
                float4 v = s4[(size_t)nc * TPN1 + l4];
                ax = (double)(w0*v.x); ay = (double)(w0*v.y);
                az = (double)(w0*v.z); aw = (double)(w0*v.w);
                sumw = (double)w0;
            }
            int p0 = ptr[nc], p1 = ptr[nc + 1];
            int p = p0 + e0;
            for (; p + 3 * EP < p1; p += 4 * EP) {
                int2 c0 = csr[p], c1 = csr[p + EP], c2 = csr[p + 2*EP], c3 = csr[p + 3*EP];
                float e0w = __int_as_float(c0.y), e1w = __int_as_float(c1.y);
                float e2w = __int_as_float(c2.y), e3w = __int_as_float(c3.y);
                float4 u0 = s4[(size_t)c0.x * TPN1 + l4];
                float4 u1 = s4[(size_t)c1.x * TPN1 + l4];
                float4 u2 = s4[(size_t)c2.x * TPN1 + l4];
                float4 u3 = s4[(size_t)c3.x * TPN1 + l4];
                ax += (double)(e0w*u0.x) + (double)(e1w*u1.x) + (double)(e2w*u2.x) + (double)(e3w*u3.x);
                ay += (double)(e0w*u0.y) + (double)(e1w*u1.y) + (double)(e2w*u2.y) + (double)(e3w*u3.y);
                az += (double)(e0w*u0.z) + (double)(e1w*u1.z) + (double)(e2w*u2.z) + (double)(e3w*u3.z);
                aw += (double)(e0w*u0.w) + (double)(e1w*u1.w) + (double)(e2w*u2.w) + (double)(e3w*u3.w);
                if (POSTAFF) sumw += (double)e0w + (double)e1w + (double)e2w + (double)e3w;
            }
            for (; p < p1; p += EP) {
                int2 ce = csr[p];
                float w = __int_as_float(ce.y);
                float4 u = s4[(size_t)ce.x * TPN1 + l4];
                ax += (double)(w*u.x); ay += (double)(w*u.y);
                az += (double)(w*u.z); aw += (double)(w*u.w);
                if (POSTAFF) sumw += (double)w;
            }
#pragma unroll
            for (int off = TPN1; off < LPN; off <<= 1) {
                ax += __shfl_xor(ax, off, 64);
                ay += __shfl_xor(ay, off, 64);
                az += __shfl_xor(az, off, 64);
                aw += __shfl_xor(aw, off, 64);
                if (POSTAFF) sumw += __shfl_xor(sumw, off, 64);
            }
            if (e0 == 0) {
                float4 acc;
                float sw = (float)sumw;
                acc.x = sc.x * (float)ax + sh.x * sw;
                acc.y = sc.y * (float)ay + sh.y * sw;
                acc.z = sc.z * (float)az + sh.z * sw;
                acc.w = sc.w * (float)aw + sh.w * sw;
                *(float4*)&hrow[nl * HS + (l4 << 2)] = acc;
            }
        }
    }
    __syncthreads();
    {
        int jq = tid % TPN2, g2 = tid / TPN2;
        float4 bv = ((const float4*)bias)[jq];
        float4 sv = {0,0,0,0}, qv = {0,0,0,0};
        for (int nl = g2; nl < NPB; nl += G2) {
            int node = nodebase + nl;
            bool valid = node < n;
            float4 a = {0.f, 0.f, 0.f, 0.f};
#pragma unroll
            for (int k4 = 0; k4 < DIN / 4; ++k4) {
                float4 hv = *(const float4*)&hrow[nl * HS + (k4 << 2)];
                const float* wb = &Wl[(k4 * 4) * DOUT + jq * 4];
                float4 w0 = *(const float4*)(wb);
                float4 w1 = *(const float4*)(wb + DOUT);
                float4 w2 = *(const float4*)(wb + 2 * DOUT);
                float4 w3 = *(const float4*)(wb + 3 * DOUT);
                a.x += hv.x*w0.x + hv.y*w1.x + hv.z*w2.x + hv.w*w3.x;
                a.y += hv.x*w0.y + hv.y*w1.y + hv.z*w2.y + hv.w*w3.y;
                a.z += hv.x*w0.z + hv.y*w1.z + hv.z*w2.z + hv.w*w3.z;
                a.w += hv.x*w0.w + hv.y*w1.w + hv.z*w2.w + hv.w*w3.w;
            }
            a.x += bv.x; a.y += bv.y; a.z += bv.z; a.w += bv.w;
            if (RELU) {
                a.x = fmaxf(a.x, 0.f); a.y = fmaxf(a.y, 0.f);
                a.z = fmaxf(a.z, 0.f); a.w = fmaxf(a.w, 0.f);
            }
            if (valid) {
                ((float4*)out)[(size_t)node * TPN2 + jq] = a;
                sv.x += a.x; sv.y += a.y; sv.z += a.z; sv.w += a.w;
                qv.x += a.x*a.x; qv.y += a.y*a.y; qv.z += a.z*a.z; qv.w += a.w*a.w;
            }
        }
        for (int off = TPN2; off < 64; off <<= 1) {
            sv.x += __shfl_down(sv.x, off, 64); sv.y += __shfl_down(sv.y, off, 64);
            sv.z += __shfl_down(sv.z, off, 64); sv.w += __shfl_down(sv.w, off, 64);
            qv.x += __shfl_down(qv.x, off, 64); qv.y += __shfl_down(qv.y, off, 64);
            qv.z += __shfl_down(qv.z, off, 64); qv.w += __shfl_down(qv.w, off, 64);
        }
        int lane = tid & 63;
        if (lane < TPN2) {
            atomicAdd(&ls[4*lane+0], (double)sv.x); atomicAdd(&ls[4*lane+1], (double)sv.y);
            atomicAdd(&ls[4*lane+2], (double)sv.z); atomicAdd(&ls[4*lane+3], (double)sv.w);
            atomicAdd(&lq[4*lane+0], (double)qv.x); atomicAdd(&lq[4*lane+1], (double)qv.y);
            atomicAdd(&lq[4*lane+2], (double)qv.z); atomicAdd(&lq[4*lane+3], (double)qv.w);
        }
        __syncthreads();
        int bkt = (blockIdx.x & (NBUCKET - 1)) * 256;
        if (tid < DOUT) {
            atomicAdd(&partOut[bkt + tid], ls[tid]);
            atomicAdd(&partOut[bkt + 128 + tid], lq[tid]);
        }
    }
}

// ---------------- wide standalone gather (L3/L4/L5): fp32 rows, f64 acc -----------------
template <int D, int POSTAFF, int PREAFF>
__global__ void __launch_bounds__(256) k_wgather(
        const float* __restrict__ src, const int* __restrict__ ptr,
        const int2* __restrict__ csr, const float* __restrict__ dis,
        const double* __restrict__ partIn, const float* __restrict__ gmv,
        const float* __restrict__ btv, float* __restrict__ out, int n) {
    const int RL = D / 4;          // lanes per row (float4 each)
    const int EP = 4;
    const int LPN = RL * EP;
    __shared__ float scs[D], shs[D];
    int tid = threadIdx.x;
    if (tid < D) bn_coef(partIn, gmv, btv, tid, n, scs, shs);
    __syncthreads();
    int t = blockIdx.x * 256 + tid;
    int node = t / LPN;
    int r = t - node * LPN;
    int e0 = r / RL;
    int l4 = r - e0 * RL;
    bool valid = node < n;
    int nc = valid ? node : n - 1;
    const float4* s4 = (const float4*)src;
    float4 sc = ((const float4*)scs)[l4], sh = ((const float4*)shs)[l4];
    double ax = 0., ay = 0., az = 0., aw = 0.;
    double sumw = 0.;
    if (e0 == 0) {
        float d = dis[nc];
        float w0 = d * d;
        float4 v = s4[(size_t)nc * RL + l4];
        if (PREAFF) AFF4(v, sc, sh);
        ax = (double)(w0*v.x); ay = (double)(w0*v.y);
        az = (double)(w0*v.z); aw = (double)(w0*v.w);
        sumw = (double)w0;
    }
    int p0 = ptr[nc], p1 = ptr[nc + 1];
    int p = p0 + e0;
    for (; p + 3 * EP < p1; p += 4 * EP) {
        int2 c0 = csr[p], c1 = csr[p + EP], c2 = csr[p + 2*EP], c3 = csr[p + 3*EP];
        float w0 = __int_as_float(c0.y), w1 = __int_as_float(c1.y);
        float w2 = __int_as_float(c2.y), w3 = __int_as_float(c3.y);
        float4 u0 = s4[(size_t)c0.x * RL + l4];
        float4 u1 = s4[(size_t)c1.x * RL + l4];
        float4 u2 = s4[(size_t)c2.x * RL + l4];
        float4 u3 = s4[(size_t)c3.x * RL + l4];
        if (PREAFF) { AFF4(u0, sc, sh); AFF4(u1, sc, sh); AFF4(u2, sc, sh); AFF4(u3, sc, sh); }
        ax += (double)(w0*u0.x) + (double)(w1*u1.x) + (double)(w2*u2.x) + (double)(w3*u3.x);
        ay += (double)(w0*u0.y) + (double)(w1*u1.y) + (double)(w2*u2.y) + (double)(w3*u3.y);
        az += (double)(w0*u0.z) + (double)(w1*u1.z) + (double)(w2*u2.z) + (double)(w3*u3.z);
        aw += (double)(w0*u0.w) + (double)(w1*u1.w) + (double)(w2*u2.w) + (double)(w3*u3.w);
        if (POSTAFF) sumw += (double)w0 + (double)w1 + (double)w2 + (double)w3;
    }
    for (; p < p1; p += EP) {
        int2 ce = csr[p];
        float w = __int_as_float(ce.y);
        float4 u = s4[(size_t)ce.x * RL + l4];
        if (PREAFF) AFF4(u, sc, sh);
        ax += (double)(w*u.x); ay += (double)(w*u.y);
        az += (double)(w*u.z); aw += (double)(w*u.w);
        if (POSTAFF) sumw += (double)w;
    }
#pragma unroll
    for (int off = RL; off < LPN; off <<= 1) {
        ax += __shfl_xor(ax, off, 64); ay += __shfl_xor(ay, off, 64);
        az += __shfl_xor(az, off, 64); aw += __shfl_xor(aw, off, 64);
        if (POSTAFF) sumw += __shfl_xor(sumw, off, 64);
    }
    if (valid && e0 == 0) {
        float4 acc;
        if (POSTAFF) {
            float sw = (float)sumw;
            acc.x = sc.x * (float)ax + sh.x * sw;
            acc.y = sc.y * (float)ay + sh.y * sw;
            acc.z = sc.z * (float)az + sh.z * sw;
            acc.w = sc.w * (float)aw + sh.w * sw;
        } else {
            acc.x = (float)ax; acc.y = (float)ay;
            acc.z = (float)az; acc.w = (float)aw;
        }
        ((float4*)out)[(size_t)nc * RL + l4] = acc;
    }
}

// ---------------- standalone gemm DIN -> DOUT, bias + optional relu + stats --------------
// POOL=1: accumulate group sums (double) into pooled[NG][DOUT] via LDS f64 aggregation.
template <int DIN, int DOUT, int RELU, int POOL>
__global__ void k_sgemm(const float* __restrict__ h, const float* __restrict__ W,
                        const float* __restrict__ bias, double* __restrict__ partOut,
                        float* __restrict__ m, const int* __restrict__ batch,
                        double* __restrict__ pooled, int n) {
    const int TPN = DOUT / 4, GPB = 256 / TPN, NPT = 4;
    const int NPBLK = GPB * NPT;
    const int MAXG = 34;
    __shared__ float Wl[DIN * DOUT];
    __shared__ double ls[DOUT], lq[DOUT];
    __shared__ double pool_l[POOL ? MAXG * DOUT : 1];
    __shared__ int gmaxs;
    int tid = threadIdx.x;
    for (int i = tid; i < DIN * DOUT / 4; i += 256)
        ((float4*)Wl)[i] = ((const float4*)W)[i];
    if (tid < DOUT) { ls[tid] = 0.; lq[tid] = 0.; }
    int gbase = 0;
    if (POOL) {
        for (int i = tid; i < MAXG * DOUT; i += 256) pool_l[i] = 0.;
        if (tid == 0) gmaxs = 0;
        int bn0 = blockIdx.x * NPBLK;
        gbase = batch[bn0 < n ? bn0 : n - 1];
    }
    __syncthreads();

    int jq = tid % TPN;
    int group = tid / TPN;
    int node0 = (blockIdx.x * GPB + group) * NPT;
    const float4* h4 = (const float4*)h;
    int hb[NPT]; bool val[NPT];
#pragma unroll
    for (int i = 0; i < NPT; ++i) {
        int nd = node0 + i;
        val[i] = nd < n;
        hb[i] = (val[i] ? nd : n - 1) * (DIN / 4);
    }
    float4 acc[NPT];
#pragma unroll
    for (int i = 0; i < NPT; ++i) acc[i] = {0.f, 0.f, 0.f, 0.f};
#pragma unroll 4
    for (int k4 = 0; k4 < DIN / 4; ++k4) {
        const float* wb = &Wl[(k4 * 4) * DOUT + jq * 4];
        float4 w0 = *(const float4*)(wb);
        float4 w1 = *(const float4*)(wb + DOUT);
        float4 w2 = *(const float4*)(wb + 2 * DOUT);
        float4 w3 = *(const float4*)(wb + 3 * DOUT);
#pragma unroll
        for (int i = 0; i < NPT; ++i) {
            float4 hv = h4[hb[i] + k4];
            acc[i].x += hv.x*w0.x + hv.y*w1.x + hv.z*w2.x + hv.w*w3.x;
            acc[i].y += hv.x*w0.y + hv.y*w1.y + hv.z*w2.y + hv.w*w3.y;
            acc[i].z += hv.x*w0.z + hv.y*w1.z + hv.z*w2.z + hv.w*w3.z;
            acc[i].w += hv.x*w0.w + hv.y*w1.w + hv.z*w2.w + hv.w*w3.w;
        }
    }
    float4 bv = ((const float4*)bias)[jq];
    float4 sv = {0,0,0,0}, qv = {0,0,0,0};
#pragma unroll
    for (int i = 0; i < NPT; ++i) {
        float4 a = acc[i];
        a.x += bv.x; a.y += bv.y; a.z += bv.z; a.w += bv.w;
        if (RELU) {
            a.x = fmaxf(a.x, 0.f); a.y = fmaxf(a.y, 0.f);
            a.z = fmaxf(a.z, 0.f); a.w = fmaxf(a.w, 0.f);
        }
        if (val[i]) {
            if (POOL) {
                int off = batch[node0 + i] - gbase;
                if (off < MAXG) {
                    atomicAdd(&pool_l[off * DOUT + jq * 4 + 0], (double)a.x);
                    atomicAdd(&pool_l[off * DOUT + jq * 4 + 1], (double)a.y);
                    atomicAdd(&pool_l[off * DOUT + jq * 4 + 2], (double)a.z);
                    atomicAdd(&pool_l[off * DOUT + jq * 4 + 3], (double)a.w);
                    if (jq == 0) atomicMax(&gmaxs, off);
                } else {
                    double* pg = &pooled[(size_t)(gbase + off) * DOUT + jq * 4];
                    atomicAdd(pg + 0, (double)a.x); atomicAdd(pg + 1, (double)a.y);
                    atomicAdd(pg + 2, (double)a.z); atomicAdd(pg + 3, (double)a.w);
                }
            } else {
                ((float4*)m)[(size_t)(node0 + i) * TPN + jq] = a;
            }
            sv.x += a.x; sv.y += a.y; sv.z += a.z; sv.w += a.w;
            qv.x += a.x*a.x; qv.y += a.y*a.y; qv.z += a.z*a.z; qv.w += a.w*a.w;
        }
    }
    for (int off = TPN; off < 64; off <<= 1) {
        sv.x += __shfl_down(sv.x, off, 64); sv.y += __shfl_down(sv.y, off, 64);
        sv.z += __shfl_down(sv.z, off, 64); sv.w += __shfl_down(sv.w, off, 64);
        qv.x += __shfl_down(qv.x, off, 64); qv.y += __shfl_down(qv.y, off, 64);
        qv.z += __shfl_down(qv.z, off, 64); qv.w += __shfl_down(qv.w, off, 64);
    }
    int lane = tid & 63;
    if (lane < TPN) {
        atomicAdd(&ls[4*lane+0], (double)sv.x); atomicAdd(&ls[4*lane+1], (double)sv.y);
        atomicAdd(&ls[4*lane+2], (double)sv.z); atomicAdd(&ls[4*lane+3], (double)sv.w);
        atomicAdd(&lq[4*lane+0], (double)qv.x); atomicAdd(&lq[4*lane+1], (double)qv.y);
        atomicAdd(&lq[4*lane+2], (double)qv.z); atomicAdd(&lq[4*lane+3], (double)qv.w);
    }
    __syncthreads();
    int bkt = (blockIdx.x & (NBUCKET - 1)) * 256;
    if (tid < DOUT) {
        atomicAdd(&partOut[bkt + tid], ls[tid]);
        atomicAdd(&partOut[bkt + 128 + tid], lq[tid]);
    }
    if (POOL) {
        int gm = gmaxs;
        for (int i = tid; i < (gm + 1) * DOUT; i += 256) {
            double v = pool_l[i];
            if (v != 0.) atomicAdd(&pooled[(size_t)gbase * DOUT + i], v);
        }
    }
}

// ---------------- pool head: BN5(from stats) applied to pooled sums + MLP ----------------
__global__ void __launch_bounds__(128) k_poolhead(
        const double* __restrict__ pooled, const int* __restrict__ batch,
        const double* __restrict__ partIn, const float* __restrict__ gmv,
        const float* __restrict__ btv,
        const float* __restrict__ fc1w, const float* __restrict__ fc1b,
        const float* __restrict__ fc2w, const float* __restrict__ fc2b,
        float* __restrict__ out, int n) {
    __shared__ float pl[128];
    __shared__ float scs[128], shs[128];
    int g = blockIdx.x;
    int tid = threadIdx.x;
    bn_coef(partIn, gmv, btv, tid, n, scs, shs);
    int a = 0, b = n;
    while (a < b) { int mid = (a + b) >> 1; if (batch[mid] < g) a = mid + 1; else b = mid; }
    int lo = a;
    b = n;
    while (a < b) { int mid = (a + b) >> 1; if (batch[mid] < g + 1) a = mid + 1; else b = mid; }
    int hi = a;
    float cntf = (float)(hi - lo);
    float p = scs[tid] * (float)pooled[g * 128 + tid] + shs[tid] * cntf;
    pl[tid] = fmaxf(p, 0.f);
    __syncthreads();
    if (tid < 64) {
        float v1 = fc1b[tid];
        for (int k = 0; k < 128; ++k) v1 += pl[k] * fc1w[k * 64 + tid];
        v1 = fmaxf(v1, 0.f);
        float v = v1 * fc2w[tid];
        for (int off = 32; off > 0; off >>= 1) v += __shfl_down(v, off, 64);
        if (tid == 0) out[g] = v + fc2b[0];
    }
}

// ---------------- driver ----------------
extern "C" void kernel_launch(void* const* d_in, const int* in_sizes, int n_in,
                              void* d_out, int out_size, void* d_ws, size_t ws_size,
                              hipStream_t stream) {
    const float* x     = (const float*)d_in[0];
    const int*   ei    = (const int*)d_in[1];
    const float* ew    = (const float*)d_in[2];
    const int*   batch = (const int*)d_in[3];
    const float *W[5], *b[5], *gm[5], *bt[5];
    for (int i = 0; i < 5; ++i) {
        W[i]  = (const float*)d_in[4 + 4 * i];
        b[i]  = (const float*)d_in[5 + 4 * i];
        gm[i] = (const float*)d_in[6 + 4 * i];
        bt[i] = (const float*)d_in[7 + 4 * i];
    }
    const float* fc1w = (const float*)d_in[24];
    const float* fc1b = (const float*)d_in[25];
    const float* fc2w = (const float*)d_in[26];
    const float* fc2b = (const float*)d_in[27];
    float* out = (float*)d_out;

    // workspace layout
    char* wsb = (char*)d_ws;
    float* dis    = (float*)wsb;  wsb += sizeof(float) * NN;
    int*   ptr    = (int*)wsb;    wsb += sizeof(int) * (NN + 4);
    int*   bb     = (int*)wsb;    wsb += sizeof(int) * ABLK * NBKT;
    int*   totals = (int*)wsb;    wsb += sizeof(int) * (NBKT + 1);
    wsb = (char*)(((uintptr_t)wsb + 15) & ~(uintptr_t)15);
    double* part   = (double*)wsb;  wsb += sizeof(double) * 5 * PARTSZ;
    double* pooled = (double*)wsb;  wsb += sizeof(double) * NG * 128;
    int2*  staging= (int2*)wsb;   wsb += sizeof(int2) * NE;
    int2*  csr    = (int2*)wsb;   wsb += sizeof(int2) * NE;
    float* bufB1  = (float*)wsb;  wsb += sizeof(float) * (size_t)NN * 64;
    float* bufB2  = (float*)wsb;  wsb += sizeof(float) * (size_t)NN * 64;
    float* buf1   = (float*)wsb;  wsb += sizeof(float) * (size_t)NN * 64;    // gathers / m1
    float* buf2   = (float*)wsb;  wsb += sizeof(float) * (size_t)NN * 16;    // L1 out

    const int* row = ei;
    const int* col = ei + NE;
    const int B = 256;
    const int NBF = (NN + 15) / 16;       // fused F2 blocks
    const int GB1 = (NN + 127) / 128;     // gemm1 blocks
    const int ZN = 5 * PARTSZ + NG * 128; // part+pooled zero region (contiguous doubles)

    // prologue: bucketed CSR build; gemm1 overlapped with kA3 (independent work)
    kA1<<<ABLK, B, 0, stream>>>(col, bb, part, ZN, NE);
    kA2a<<<NBKT, B, 0, stream>>>(bb, totals);
    kA3g<<<ABLK + GB1, B, 0, stream>>>(row, col, ew, bb, totals, staging, x, W[0], buf1, NE, NN);
    kB<<<NBKT, B, 0, stream>>>(totals, staging, csr, ptr, dis, NN);

    // L1 gather (f64 acc): bias+relu+stats + CSR rescale write-back (fp32 weights)
    k_l1gather<<<(NN * 4 + 255) / 256, B, 0, stream>>>(buf1, ptr, csr, dis,
                                                       b[0], part + 0 * PARTSZ, buf2, NN);

    // F2: 16->32 fused, consume part[0] (BN1 hoisted), fp32 in/out
    k_fused<16, 32, 4, 1, 1, 16><<<NBF, B, 0, stream>>>(
        buf2, ptr, csr, dis, part + 0 * PARTSZ, gm[0], bt[0],
        W[1], b[1], part + 1 * PARTSZ, bufB1, NN);

    // L3: gather32 (BN2 hoisted, f64 acc) then gemm 32->64 (+relu)
    k_wgather<32, 1, 0><<<(int)(((long)NN * 32 + 255) / 256), B, 0, stream>>>(
        bufB1, ptr, csr, dis, part + 1 * PARTSZ, gm[1], bt[1], buf1, NN);
    k_sgemm<32, 64, 1, 0><<<(NN + 63) / 64, B, 0, stream>>>(
        buf1, W[2], b[2], part + 2 * PARTSZ, bufB2, nullptr, nullptr, NN);

    // L4: gather64 (BN3 hoisted) then gemm 64->64 (no relu; BN4 stats)
    k_wgather<64, 1, 0><<<(int)(((long)NN * 64 + 255) / 256), B, 0, stream>>>(
        bufB2, ptr, csr, dis, part + 2 * PARTSZ, gm[2], bt[2], buf1, NN);
    k_sgemm<64, 64, 0, 0><<<(NN + 63) / 64, B, 0, stream>>>(
        buf1, W[3], b[3], part + 3 * PARTSZ, bufB1, nullptr, nullptr, NN);

    // L5: gather64 (per-edge relu(BN4)) then gemm 64->128 fused with pool (f64 sums)
    k_wgather<64, 0, 1><<<(int)(((long)NN * 64 + 255) / 256), B, 0, stream>>>(
        bufB1, ptr, csr, dis, part + 3 * PARTSZ, gm[3], bt[3], buf1, NN);
    k_sgemm<64, 128, 0, 1><<<(NN + 31) / 32, B, 0, stream>>>(
        buf1, W[4], b[4], part + 4 * PARTSZ, nullptr, batch, pooled, NN);

    // head: BN5 (stats from part[4]) on pooled sums + MLP
    k_poolhead<<<NG, 128, 0, stream>>>(pooled, batch, part + 4 * PARTSZ, gm[4], bt[4],
                                       fc1w, fc1b, fc2w, fc2b, out, NN);
}

// Round 7
// 369.433 us; speedup vs baseline: 1.1533x; 1.0357x over previous
//
#include <hip/hip_runtime.h>
#include <hip/hip_fp16.h>
#include <stdint.h>

#define NN 50000
#define NE 800000
#define NG 256
#define NBUCKET 16
#define PARTSZ (NBUCKET * 256)

// bucketed CSR build params
#define NBKT 391      // node buckets of 128
#define ABLK 391
#define ASLICE 2048
#define BCAP 2560

__device__ __forceinline__ unsigned short f2h(float f) {
    __half h = __float2half(f);
    return *(unsigned short*)&h;
}
__device__ __forceinline__ float h2f(unsigned short u) {
    __half h = *(__half*)&u;
    return __half2float(h);
}

#define AFF4(u, sc, sh) { u.x = fmaxf(sc.x*u.x+sh.x,0.f); u.y = fmaxf(sc.y*u.y+sh.y,0.f); \
                          u.z = fmaxf(sc.z*u.z+sh.z,0.f); u.w = fmaxf(sc.w*u.w+sh.w,0.f); }

// BN coefficients from double-precision partial sums (replay-stable)
__device__ __forceinline__ void bn_coef(const double* __restrict__ partIn,
                                        const float* __restrict__ gmv,
                                        const float* __restrict__ btv,
                                        int tid, int n, float* scs, float* shs) {
    double s = 0., q = 0.;
#pragma unroll
    for (int b2 = 0; b2 < NBUCKET; ++b2) {
        s += partIn[b2 * 256 + tid];
        q += partIn[b2 * 256 + 128 + tid];
    }
    double mu = s / (double)n;
    double var = q / (double)n - mu * mu;
    float a = gmv[tid] * rsqrtf((float)var + 1e-5f);
    scs[tid] = a;
    shs[tid] = btv[tid] - (float)mu * a;
}

// wave-parallel exclusive scan of totals[0..NBKT) into sbase[0..NBKT] (sbase[NBKT]=sum)
__device__ __forceinline__ void scan_totals(const int* __restrict__ totals,
                                            int* __restrict__ sbase, int tid) {
    if (tid < 64) {
        const int C = (NBKT + 63) / 64;  // 7
        int tv[C];
        int s = 0;
        int i0 = tid * C;
#pragma unroll
        for (int j = 0; j < C; ++j) {
            int idx = i0 + j;
            int x = (idx < NBKT) ? totals[idx] : 0;
            tv[j] = x; s += x;
        }
        int inc = s;
        for (int off = 1; off < 64; off <<= 1) {
            int t2 = __shfl_up(inc, off, 64);
            if (tid >= off) inc += t2;
        }
        int run = inc - s;
#pragma unroll
        for (int j = 0; j < C; ++j) {
            int idx = i0 + j;
            if (idx < NBKT) sbase[idx] = run;
            run += tv[j];
        }
        if (tid == 63) sbase[NBKT] = run;
    }
}

// ---------------- prologue ----------------
__global__ void kA1(const int* __restrict__ col, int* __restrict__ bb,
                    double* __restrict__ zz, int zn, int e) {
    __shared__ int cnt[NBKT];
    for (int j = threadIdx.x; j < NBKT; j += 256) cnt[j] = 0;
    for (int i = blockIdx.x * 256 + threadIdx.x; i < zn; i += ABLK * 256) zz[i] = 0.;
    __syncthreads();
    int start = blockIdx.x * ASLICE;
    int end = min(start + ASLICE, e);
    for (int i = start + threadIdx.x; i < end; i += 256)
        atomicAdd(&cnt[col[i] >> 7], 1);
    __syncthreads();
    for (int j = threadIdx.x; j < NBKT; j += 256) bb[blockIdx.x * NBKT + j] = cnt[j];
}

__global__ void kA2a(int* __restrict__ bb, int* __restrict__ totals) {
    __shared__ int v[ABLK];
    int k = blockIdx.x;
    int tid = threadIdx.x;
    for (int b = tid; b < ABLK; b += 256) v[b] = bb[b * NBKT + k];
    __syncthreads();
    if (tid < 64) {
        const int C = (ABLK + 63) / 64;  // 7
        int tv[C];
        int s = 0;
        int i0 = tid * C;
#pragma unroll
        for (int j = 0; j < C; ++j) {
            int idx = i0 + j;
            int x = (idx < ABLK) ? v[idx] : 0;
            tv[j] = x; s += x;
        }
        int inc = s;
        for (int off = 1; off < 64; off <<= 1) {
            int t2 = __shfl_up(inc, off, 64);
            if (tid >= off) inc += t2;
        }
        int run = inc - s;
#pragma unroll
        for (int j = 0; j < C; ++j) {
            int idx = i0 + j;
            if (idx < ABLK) v[idx] = run;
            run += tv[j];
        }
        if (tid == 63) totals[k] = run;
    }
    __syncthreads();
    for (int b = tid; b < ABLK; b += 256) bb[b * NBKT + k] = v[b];
}

// A3 (blocks [0,ABLK)) + independent L1 gemm 128->16 (blocks [ABLK,..)) in one dispatch
__global__ void kA3g(const int* __restrict__ row, const int* __restrict__ col,
                     const float* __restrict__ ew, const int* __restrict__ bb,
                     const int* __restrict__ totals, int2* __restrict__ staging,
                     const float* __restrict__ x, const float* __restrict__ W0,
                     float* __restrict__ m1, int e, int n) {
    __shared__ int cur[NBKT];
    __shared__ int sbase[NBKT + 1];
    __shared__ float Wl[128 * 16];
    int tid = threadIdx.x;
    if ((int)blockIdx.x < ABLK) {
        scan_totals(totals, sbase, tid);
        __syncthreads();
        for (int j = tid; j < NBKT; j += 256)
            cur[j] = sbase[j] + bb[blockIdx.x * NBKT + j];
        __syncthreads();
        int start = blockIdx.x * ASLICE;
        int end = min(start + ASLICE, e);
        for (int i = start + tid; i < end; i += 256) {
            int c = col[i];
            int p = atomicAdd(&cur[c >> 7], 1);
            staging[p] = make_int2(row[i] | ((c & 127) << 16), __float_as_int(ew[i]));
        }
        return;
    }
    int bid = (int)blockIdx.x - ABLK;
    for (int i = tid; i < 128 * 16 / 4; i += 256)
        ((float4*)Wl)[i] = ((const float4*)W0)[i];
    __syncthreads();
    int jq = tid % 4, group = tid / 4;
    int node0 = (bid * 64 + group) * 2;
    const float4* h4 = (const float4*)x;
    int hb[2]; bool val[2];
#pragma unroll
    for (int i = 0; i < 2; ++i) {
        int nd = node0 + i;
        val[i] = nd < n;
        hb[i] = (val[i] ? nd : n - 1) * 32;
    }
    float4 acc[2];
    acc[0] = {0,0,0,0}; acc[1] = {0,0,0,0};
#pragma unroll 4
    for (int k4 = 0; k4 < 32; ++k4) {
        const float* wb = &Wl[(k4 * 4) * 16 + jq * 4];
        float4 w0 = *(const float4*)(wb);
        float4 w1 = *(const float4*)(wb + 16);
        float4 w2 = *(const float4*)(wb + 32);
        float4 w3 = *(const float4*)(wb + 48);
#pragma unroll
        for (int i = 0; i < 2; ++i) {
            float4 hv = h4[hb[i] + k4];
            acc[i].x += hv.x*w0.x + hv.y*w1.x + hv.z*w2.x + hv.w*w3.x;
            acc[i].y += hv.x*w0.y + hv.y*w1.y + hv.z*w2.y + hv.w*w3.y;
            acc[i].z += hv.x*w0.z + hv.y*w1.z + hv.z*w2.z + hv.w*w3.z;
            acc[i].w += hv.x*w0.w + hv.y*w1.w + hv.z*w2.w + hv.w*w3.w;
        }
    }
#pragma unroll
    for (int i = 0; i < 2; ++i)
        if (val[i]) ((float4*)m1)[(node0 + i) * 4 + jq] = acc[i];
}

// csr entry: .x = src node id, .y = fp32 weight bits; degree summed in f64 (order-robust)
__global__ void __launch_bounds__(256) kB(const int* __restrict__ totals,
                                          const int2* __restrict__ staging,
                                          int2* __restrict__ csr, int* __restrict__ ptr,
                                          float* __restrict__ dis, int n) {
    __shared__ int2 st[BCAP];
    __shared__ int2 outb[BCAP];
    __shared__ int hist[129];
    __shared__ int cur[128];
    __shared__ int sbase[NBKT + 1];
    int k = blockIdx.x, t = threadIdx.x;
    scan_totals(totals, sbase, t);
    if (t < 129) hist[t] = 0;
    __syncthreads();
    int base = sbase[k], cnt = sbase[k + 1] - sbase[k];
    int node0 = k << 7;
    int ncov = min(128, n - node0);
    if (cnt <= BCAP) {
        for (int i = t; i < cnt; i += 256) {
            int2 v = staging[base + i];
            st[i] = v;
            atomicAdd(&hist[v.x >> 16], 1);
        }
        __syncthreads();
        if (t == 0) {
            int run = 0;
            for (int j = 0; j < 128; ++j) { int h = hist[j]; hist[j] = run; run += h; }
            hist[128] = run;
        }
        __syncthreads();
        if (t < 128) cur[t] = hist[t];
        if (t < ncov) ptr[node0 + t] = base + hist[t];
        __syncthreads();
        for (int i = t; i < cnt; i += 256) {
            int2 v = st[i];
            int j = v.x >> 16;
            int p = atomicAdd(&cur[j], 1);
            outb[p] = make_int2(v.x & 0xFFFF, v.y);
        }
        __syncthreads();
        for (int i = t; i < cnt; i += 256) csr[base + i] = outb[i];
        if (t < ncov) {
            double s = 1.;
            int a = hist[t], b2 = hist[t + 1];
            for (int p = a; p < b2; ++p) s += (double)__int_as_float(outb[p].y);
            dis[node0 + t] = rsqrtf((float)s);
        }
    } else {
        for (int i = t; i < cnt; i += 256) atomicAdd(&hist[staging[base + i].x >> 16], 1);
        __syncthreads();
        if (t == 0) {
            int run = 0;
            for (int j = 0; j < 128; ++j) { int h = hist[j]; hist[j] = run; run += h; }
            hist[128] = run;
        }
        __syncthreads();
        if (t < 128) cur[t] = hist[t];
        if (t < ncov) ptr[node0 + t] = base + hist[t];
        __syncthreads();
        for (int i = t; i < cnt; i += 256) {
            int2 v = staging[base + i];
            int j = v.x >> 16;
            int p = atomicAdd(&cur[j], 1);
            csr[base + p] = make_int2(v.x & 0xFFFF, v.y);
        }
        __threadfence_block();
        __syncthreads();
        if (t < ncov) {
            double s = 1.;
            int a = hist[t], b2 = hist[t + 1];
            for (int p = a; p < b2; ++p) s += (double)__int_as_float(csr[base + p].y);
            dis[node0 + t] = rsqrtf((float)s);
        }
    }
    if (k == gridDim.x - 1 && t == 0) ptr[n] = sbase[NBKT];
}

// ---------------- L1 gather: f64 acc, EPI (bias+relu+stats) + CSR rescale write-back -----
__global__ void k_l1gather(const float* __restrict__ src, const int* __restrict__ ptr,
                           int2* __restrict__ csr, const float* __restrict__ dis,
                           const float* __restrict__ bias, double* __restrict__ partOut,
                           float* __restrict__ out, int n) {
    int tid = threadIdx.x;
    int t = blockIdx.x * 256 + tid;
    int node = t >> 2;
    int l4 = t & 3;
    bool valid = node < n;
    int nc = valid ? node : n - 1;
    const float4* s4 = (const float4*)src;
    float dc = dis[nc];
    float w0 = dc * dc;
    float4 v = s4[nc * 4 + l4];
    double ax = (double)(w0 * v.x), ay = (double)(w0 * v.y);
    double az = (double)(w0 * v.z), aw = (double)(w0 * v.w);
    int p0 = ptr[nc], p1 = ptr[nc + 1];
    int p = p0;
    for (; p + 4 <= p1; p += 4) {
        int2 c0 = csr[p], c1 = csr[p+1], c2 = csr[p+2], c3 = csr[p+3];
        float e0 = dis[c0.x] * __int_as_float(c0.y) * dc;
        float e1 = dis[c1.x] * __int_as_float(c1.y) * dc;
        float e2 = dis[c2.x] * __int_as_float(c2.y) * dc;
        float e3 = dis[c3.x] * __int_as_float(c3.y) * dc;
        float4 u0 = s4[c0.x * 4 + l4];
        float4 u1 = s4[c1.x * 4 + l4];
        float4 u2 = s4[c2.x * 4 + l4];
        float4 u3 = s4[c3.x * 4 + l4];
        ax += (double)(e0*u0.x) + (double)(e1*u1.x) + (double)(e2*u2.x) + (double)(e3*u3.x);
        ay += (double)(e0*u0.y) + (double)(e1*u1.y) + (double)(e2*u2.y) + (double)(e3*u3.y);
        az += (double)(e0*u0.z) + (double)(e1*u1.z) + (double)(e2*u2.z) + (double)(e3*u3.z);
        aw += (double)(e0*u0.w) + (double)(e1*u1.w) + (double)(e2*u2.w) + (double)(e3*u3.w);
        if (l4 == 0) {
            csr[p]   = make_int2(c0.x, __float_as_int(e0));
            csr[p+1] = make_int2(c1.x, __float_as_int(e1));
            csr[p+2] = make_int2(c2.x, __float_as_int(e2));
            csr[p+3] = make_int2(c3.x, __float_as_int(e3));
        }
    }
    for (; p < p1; ++p) {
        int2 ce = csr[p];
        float w = dis[ce.x] * __int_as_float(ce.y) * dc;
        float4 u = s4[ce.x * 4 + l4];
        ax += (double)(w*u.x); ay += (double)(w*u.y);
        az += (double)(w*u.z); aw += (double)(w*u.w);
        if (l4 == 0) csr[p] = make_int2(ce.x, __float_as_int(w));
    }
    float4 b = ((const float4*)bias)[l4];
    float4 acc;
    acc.x = fmaxf((float)ax + b.x, 0.f);
    acc.y = fmaxf((float)ay + b.y, 0.f);
    acc.z = fmaxf((float)az + b.z, 0.f);
    acc.w = fmaxf((float)aw + b.w, 0.f);
    if (valid) ((float4*)out)[nc * 4 + l4] = acc;
    float s0 = valid ? acc.x : 0.f, s1 = valid ? acc.y : 0.f;
    float s2 = valid ? acc.z : 0.f, s3 = valid ? acc.w : 0.f;
    float q0 = s0*s0, q1 = s1*s1, q2 = s2*s2, q3 = s3*s3;
    for (int off = 4; off < 64; off <<= 1) {
        s0 += __shfl_down(s0, off, 64); s1 += __shfl_down(s1, off, 64);
        s2 += __shfl_down(s2, off, 64); s3 += __shfl_down(s3, off, 64);
        q0 += __shfl_down(q0, off, 64); q1 += __shfl_down(q1, off, 64);
        q2 += __shfl_down(q2, off, 64); q3 += __shfl_down(q3, off, 64);
    }
    int lane = tid & 63;
    int bkt = (blockIdx.x & (NBUCKET - 1)) * 256;
    if (lane < 4) {
        atomicAdd(&partOut[bkt + 4*lane + 0], (double)s0);
        atomicAdd(&partOut[bkt + 4*lane + 1], (double)s1);
        atomicAdd(&partOut[bkt + 4*lane + 2], (double)s2);
        atomicAdd(&partOut[bkt + 4*lane + 3], (double)s3);
        atomicAdd(&partOut[bkt + 128 + 4*lane + 0], (double)q0);
        atomicAdd(&partOut[bkt + 128 + 4*lane + 1], (double)q1);
        atomicAdd(&partOut[bkt + 128 + 4*lane + 2], (double)q2);
        atomicAdd(&partOut[bkt + 128 + 4*lane + 3], (double)q3);
    }
}

// 16B-wide fp16 row loader: 8 fp16 per lane -> two float4
template <int D>
__device__ __forceinline__ void ldrow16(const unsigned short* __restrict__ src, int node, int l8,
                                        float4& a, float4& b) {
    uint4 r = *(const uint4*)(src + (size_t)node * D + (l8 << 3));
    a.x = h2f((unsigned short)(r.x)); a.y = h2f((unsigned short)(r.x >> 16));
    a.z = h2f((unsigned short)(r.y)); a.w = h2f((unsigned short)(r.y >> 16));
    b.x = h2f((unsigned short)(r.z)); b.y = h2f((unsigned short)(r.z >> 16));
    b.z = h2f((unsigned short)(r.w)); b.w = h2f((unsigned short)(r.w >> 16));
}

// ---------------- fused layer F2 (16->32): gather (f64 acc, fp32 src) -> gemm, fp16 out --
template <int DIN, int DOUT, int EP, int RELU, int NPB>
__global__ void __launch_bounds__(256) k_fused(
        const float* __restrict__ src, const int* __restrict__ ptr,
        const int2* __restrict__ csr, const float* __restrict__ dis,
        const double* __restrict__ partIn, const float* __restrict__ gmv,
        const float* __restrict__ btv, const float* __restrict__ W,
        const float* __restrict__ bias, double* __restrict__ partOut,
        unsigned short* __restrict__ out, int n) {
    const int TPN1 = DIN / 4, LPN = TPN1 * EP, GN1 = 256 / LPN;
    const int TPN2 = DOUT / 4, G2 = 256 / TPN2;
    const int HS = DIN + 4;
    __shared__ float Wl[DIN * DOUT];
    __shared__ float hrow[NPB * HS];
    __shared__ float scs[DIN], shs[DIN];
    __shared__ double ls[DOUT], lq[DOUT];
    int tid = threadIdx.x;
    for (int i = tid; i < DIN * DOUT / 4; i += 256)
        ((float4*)Wl)[i] = ((const float4*)W)[i];
    if (tid < DIN) bn_coef(partIn, gmv, btv, tid, n, scs, shs);
    if (tid < DOUT) { ls[tid] = 0.; lq[tid] = 0.; }
    __syncthreads();

    int nodebase = blockIdx.x * NPB;
    {
        int grp = tid / LPN, r = tid % LPN;
        int e0 = r / TPN1, l4 = r % TPN1;
        float4 sc = ((const float4*)scs)[l4];
        float4 sh = ((const float4*)shs)[l4];
        const float4* s4 = (const float4*)src;
#pragma unroll
        for (int pass = 0; pass < NPB / GN1; ++pass) {
            int nl = pass * GN1 + grp;
            int node = nodebase + nl;
            int nc = node < n ? node : n - 1;
            double ax = 0., ay = 0., az = 0., aw = 0.;
            double sumw = 0.;
            if (e0 == 0) {
                float d = dis[nc];
                float w0 = d * d;
                float4 v = s4[(size_t)nc * TPN1 + l4];
                ax = (double)(w0*v.x); ay = (double)(w0*v.y);
                az = (double)(w0*v.z); aw = (double)(w0*v.w);
                sumw = (double)w0;
            }
            int p0 = ptr[nc], p1 = ptr[nc + 1];
            int p = p0 + e0;
            for (; p + 3 * EP < p1; p += 4 * EP) {
                int2 c0 = csr[p], c1 = csr[p + EP], c2 = csr[p + 2*EP], c3 = csr[p + 3*EP];
                float e0w = __int_as_float(c0.y), e1w = __int_as_float(c1.y);
                float e2w = __int_as_float(c2.y), e3w = __int_as_float(c3.y);
                float4 u0 = s4[(size_t)c0.x * TPN1 + l4];
                float4 u1 = s4[(size_t)c1.x * TPN1 + l4];
                float4 u2 = s4[(size_t)c2.x * TPN1 + l4];
                float4 u3 = s4[(size_t)c3.x * TPN1 + l4];
                ax += (double)(e0w*u0.x) + (double)(e1w*u1.x) + (double)(e2w*u2.x) + (double)(e3w*u3.x);
                ay += (double)(e0w*u0.y) + (double)(e1w*u1.y) + (double)(e2w*u2.y) + (double)(e3w*u3.y);
                az += (double)(e0w*u0.z) + (double)(e1w*u1.z) + (double)(e2w*u2.z) + (double)(e3w*u3.z);
                aw += (double)(e0w*u0.w) + (double)(e1w*u1.w) + (double)(e2w*u2.w) + (double)(e3w*u3.w);
                sumw += (double)e0w + (double)e1w + (double)e2w + (double)e3w;
            }
            for (; p < p1; p += EP) {
                int2 ce = csr[p];
                float w = __int_as_float(ce.y);
                float4 u = s4[(size_t)ce.x * TPN1 + l4];
                ax += (double)(w*u.x); ay += (double)(w*u.y);
                az += (double)(w*u.z); aw += (double)(w*u.w);
                sumw += (double)w;
            }
#pragma unroll
            for (int off = TPN1; off < LPN; off <<= 1) {
                ax += __shfl_xor(ax, off, 64);
                ay += __shfl_xor(ay, off, 64);
                az += __shfl_xor(az, off, 64);
                aw += __shfl_xor(aw, off, 64);
                sumw += __shfl_xor(sumw, off, 64);
            }
            if (e0 == 0) {
                float4 acc;
                float sw = (float)sumw;
                acc.x = sc.x * (float)ax + sh.x * sw;
                acc.y = sc.y * (float)ay + sh.y * sw;
                acc.z = sc.z * (float)az + sh.z * sw;
                acc.w = sc.w * (float)aw + sh.w * sw;
                *(float4*)&hrow[nl * HS + (l4 << 2)] = acc;
            }
        }
    }
    __syncthreads();
    {
        int jq = tid % TPN2, g2 = tid / TPN2;
        float4 bv = ((const float4*)bias)[jq];
        float4 sv = {0,0,0,0}, qv = {0,0,0,0};
        for (int nl = g2; nl < NPB; nl += G2) {
            int node = nodebase + nl;
            bool valid = node < n;
            float4 a = {0.f, 0.f, 0.f, 0.f};
#pragma unroll
            for (int k4 = 0; k4 < DIN / 4; ++k4) {
                float4 hv = *(const float4*)&hrow[nl * HS + (k4 << 2)];
                const float* wb = &Wl[(k4 * 4) * DOUT + jq * 4];
                float4 w0 = *(const float4*)(wb);
                float4 w1 = *(const float4*)(wb + DOUT);
                float4 w2 = *(const float4*)(wb + 2 * DOUT);
                float4 w3 = *(const float4*)(wb + 3 * DOUT);
                a.x += hv.x*w0.x + hv.y*w1.x + hv.z*w2.x + hv.w*w3.x;
                a.y += hv.x*w0.y + hv.y*w1.y + hv.z*w2.y + hv.w*w3.y;
                a.z += hv.x*w0.z + hv.y*w1.z + hv.z*w2.z + hv.w*w3.z;
                a.w += hv.x*w0.w + hv.y*w1.w + hv.z*w2.w + hv.w*w3.w;
            }
            a.x += bv.x; a.y += bv.y; a.z += bv.z; a.w += bv.w;
            if (RELU) {
                a.x = fmaxf(a.x, 0.f); a.y = fmaxf(a.y, 0.f);
                a.z = fmaxf(a.z, 0.f); a.w = fmaxf(a.w, 0.f);
            }
            if (valid) {
                ushort4 o;
                o.x = f2h(a.x); o.y = f2h(a.y); o.z = f2h(a.z); o.w = f2h(a.w);
                *(ushort4*)(out + (size_t)node * DOUT + (jq << 2)) = o;
                sv.x += a.x; sv.y += a.y; sv.z += a.z; sv.w += a.w;
                qv.x += a.x*a.x; qv.y += a.y*a.y; qv.z += a.z*a.z; qv.w += a.w*a.w;
            }
        }
        for (int off = TPN2; off < 64; off <<= 1) {
            sv.x += __shfl_down(sv.x, off, 64); sv.y += __shfl_down(sv.y, off, 64);
            sv.z += __shfl_down(sv.z, off, 64); sv.w += __shfl_down(sv.w, off, 64);
            qv.x += __shfl_down(qv.x, off, 64); qv.y += __shfl_down(qv.y, off, 64);
            qv.z += __shfl_down(qv.z, off, 64); qv.w += __shfl_down(qv.w, off, 64);
        }
        int lane = tid & 63;
        if (lane < TPN2) {
            atomicAdd(&ls[4*lane+0], (double)sv.x); atomicAdd(&ls[4*lane+1], (double)sv.y);
            atomicAdd(&ls[4*lane+2], (double)sv.z); atomicAdd(&ls[4*lane+3], (double)sv.w);
            atomicAdd(&lq[4*lane+0], (double)qv.x); atomicAdd(&lq[4*lane+1], (double)qv.y);
            atomicAdd(&lq[4*lane+2], (double)qv.z); atomicAdd(&lq[4*lane+3], (double)qv.w);
        }
        __syncthreads();
        int bkt = (blockIdx.x & (NBUCKET - 1)) * 256;
        if (tid < DOUT) {
            atomicAdd(&partOut[bkt + tid], ls[tid]);
            atomicAdd(&partOut[bkt + 128 + tid], lq[tid]);
        }
    }
}

// ---------------- wide standalone gather (L3/L4/L5): fp16 rows (16B loads), f64 acc ------
template <int D, int POSTAFF, int PREAFF>
__global__ void __launch_bounds__(256) k_wgather(
        const unsigned short* __restrict__ src, const int* __restrict__ ptr,
        const int2* __restrict__ csr, const float* __restrict__ dis,
        const double* __restrict__ partIn, const float* __restrict__ gmv,
        const float* __restrict__ btv, float* __restrict__ out, int n) {
    const int RL = D / 8;          // lanes per row (8 fp16 = 16B each)
    const int EP = 4;
    const int LPN = RL * EP;
    __shared__ float scs[D], shs[D];
    int tid = threadIdx.x;
    if (tid < D) bn_coef(partIn, gmv, btv, tid, n, scs, shs);
    __syncthreads();
    int t = blockIdx.x * 256 + tid;
    int node = t / LPN;
    int r = t - node * LPN;
    int e0 = r / RL;
    int l8 = r - e0 * RL;
    bool valid = node < n;
    int nc = valid ? node : n - 1;
    float4 scA = ((const float4*)scs)[l8 * 2],     shA = ((const float4*)shs)[l8 * 2];
    float4 scB = ((const float4*)scs)[l8 * 2 + 1], shB = ((const float4*)shs)[l8 * 2 + 1];
    double aAx=0., aAy=0., aAz=0., aAw=0.;
    double aBx=0., aBy=0., aBz=0., aBw=0.;
    double sumw = 0.;
    if (e0 == 0) {
        float d = dis[nc];
        float w0 = d * d;
        float4 a, b2;
        ldrow16<D>(src, nc, l8, a, b2);
        if (PREAFF) { AFF4(a, scA, shA); AFF4(b2, scB, shB); }
        aAx = (double)(w0*a.x);  aAy = (double)(w0*a.y);
        aAz = (double)(w0*a.z);  aAw = (double)(w0*a.w);
        aBx = (double)(w0*b2.x); aBy = (double)(w0*b2.y);
        aBz = (double)(w0*b2.z); aBw = (double)(w0*b2.w);
        sumw = (double)w0;
    }
    int p0 = ptr[nc], p1 = ptr[nc + 1];
    int p = p0 + e0;
    for (; p + 3 * EP < p1; p += 4 * EP) {
        int2 c0 = csr[p], c1 = csr[p + EP], c2 = csr[p + 2*EP], c3 = csr[p + 3*EP];
        float w0 = __int_as_float(c0.y), w1 = __int_as_float(c1.y);
        float w2 = __int_as_float(c2.y), w3 = __int_as_float(c3.y);
        float4 a0, b0, a1, b1, a2, b2, a3, b3;
        ldrow16<D>(src, c0.x, l8, a0, b0);
        ldrow16<D>(src, c1.x, l8, a1, b1);
        ldrow16<D>(src, c2.x, l8, a2, b2);
        ldrow16<D>(src, c3.x, l8, a3, b3);
        if (PREAFF) {
            AFF4(a0, scA, shA); AFF4(b0, scB, shB);
            AFF4(a1, scA, shA); AFF4(b1, scB, shB);
            AFF4(a2, scA, shA); AFF4(b2, scB, shB);
            AFF4(a3, scA, shA); AFF4(b3, scB, shB);
        }
        aAx += (double)(w0*a0.x) + (double)(w1*a1.x) + (double)(w2*a2.x) + (double)(w3*a3.x);
        aAy += (double)(w0*a0.y) + (double)(w1*a1.y) + (double)(w2*a2.y) + (double)(w3*a3.y);
        aAz += (double)(w0*a0.z) + (double)(w1*a1.z) + (double)(w2*a2.z) + (double)(w3*a3.z);
        aAw += (double)(w0*a0.w) + (double)(w1*a1.w) + (double)(w2*a2.w) + (double)(w3*a3.w);
        aBx += (double)(w0*b0.x) + (double)(w1*b1.x) + (double)(w2*b2.x) + (double)(w3*b3.x);
        aBy += (double)(w0*b0.y) + (double)(w1*b1.y) + (double)(w2*b2.y) + (double)(w3*b3.y);
        aBz += (double)(w0*b0.z) + (double)(w1*b1.z) + (double)(w2*b2.z) + (double)(w3*b3.z);
        aBw += (double)(w0*b0.w) + (double)(w1*b1.w) + (double)(w2*b2.w) + (double)(w3*b3.w);
        if (POSTAFF) sumw += (double)w0 + (double)w1 + (double)w2 + (double)w3;
    }
    for (; p < p1; p += EP) {
        int2 ce = csr[p];
        float w = __int_as_float(ce.y);
        float4 a, b2;
        ldrow16<D>(src, ce.x, l8, a, b2);
        if (PREAFF) { AFF4(a, scA, shA); AFF4(b2, scB, shB); }
        aAx += (double)(w*a.x);  aAy += (double)(w*a.y);
        aAz += (double)(w*a.z);  aAw += (double)(w*a.w);
        aBx += (double)(w*b2.x); aBy += (double)(w*b2.y);
        aBz += (double)(w*b2.z); aBw += (double)(w*b2.w);
        if (POSTAFF) sumw += (double)w;
    }
#pragma unroll
    for (int off = RL; off < LPN; off <<= 1) {
        aAx += __shfl_xor(aAx, off, 64); aAy += __shfl_xor(aAy, off, 64);
        aAz += __shfl_xor(aAz, off, 64); aAw += __shfl_xor(aAw, off, 64);
        aBx += __shfl_xor(aBx, off, 64); aBy += __shfl_xor(aBy, off, 64);
        aBz += __shfl_xor(aBz, off, 64); aBw += __shfl_xor(aBw, off, 64);
        if (POSTAFF) sumw += __shfl_xor(sumw, off, 64);
    }
    if (valid && e0 == 0) {
        float4 accA, accB;
        if (POSTAFF) {
            float sw = (float)sumw;
            accA.x = scA.x * (float)aAx + shA.x * sw;
            accA.y = scA.y * (float)aAy + shA.y * sw;
            accA.z = scA.z * (float)aAz + shA.z * sw;
            accA.w = scA.w * (float)aAw + shA.w * sw;
            accB.x = scB.x * (float)aBx + shB.x * sw;
            accB.y = scB.y * (float)aBy + shB.y * sw;
            accB.z = scB.z * (float)aBz + shB.z * sw;
            accB.w = scB.w * (float)aBw + shB.w * sw;
        } else {
            accA.x = (float)aAx; accA.y = (float)aAy;
            accA.z = (float)aAz; accA.w = (float)aAw;
            accB.x = (float)aBx; accB.y = (float)aBy;
            accB.z = (float)aBz; accB.w = (float)aBw;
        }
        ((float4*)out)[(size_t)nc * (D / 4) + l8 * 2]     = accA;
        ((float4*)out)[(size_t)nc * (D / 4) + l8 * 2 + 1] = accB;
    }
}

// ---------------- standalone gemm DIN -> DOUT, bias + optional relu + stats --------------
// F16OUT: store fp16; POOL=1: accumulate group sums (double) into pooled[NG][DOUT]
template <int DIN, int DOUT, int RELU, int F16OUT, int POOL>
__global__ void k_sgemm(const float* __restrict__ h, const float* __restrict__ W,
                        const float* __restrict__ bias, double* __restrict__ partOut,
                        void* __restrict__ m, const int* __restrict__ batch,
                        double* __restrict__ pooled, int n) {
    const int TPN = DOUT / 4, GPB = 256 / TPN, NPT = 4;
    const int NPBLK = GPB * NPT;
    const int MAXG = 34;
    __shared__ float Wl[DIN * DOUT];
    __shared__ double ls[DOUT], lq[DOUT];
    __shared__ double pool_l[POOL ? MAXG * DOUT : 1];
    __shared__ int gmaxs;
    int tid = threadIdx.x;
    for (int i = tid; i < DIN * DOUT / 4; i += 256)
        ((float4*)Wl)[i] = ((const float4*)W)[i];
    if (tid < DOUT) { ls[tid] = 0.; lq[tid] = 0.; }
    int gbase = 0;
    if (POOL) {
        for (int i = tid; i < MAXG * DOUT; i += 256) pool_l[i] = 0.;
        if (tid == 0) gmaxs = 0;
        int bn0 = blockIdx.x * NPBLK;
        gbase = batch[bn0 < n ? bn0 : n - 1];
    }
    __syncthreads();

    int jq = tid % TPN;
    int group = tid / TPN;
    int node0 = (blockIdx.x * GPB + group) * NPT;
    const float4* h4 = (const float4*)h;
    int hb[NPT]; bool val[NPT];
#pragma unroll
    for (int i = 0; i < NPT; ++i) {
        int nd = node0 + i;
        val[i] = nd < n;
        hb[i] = (val[i] ? nd : n - 1) * (DIN / 4);
    }
    float4 acc[NPT];
#pragma unroll
    for (int i = 0; i < NPT; ++i) acc[i] = {0.f, 0.f, 0.f, 0.f};
#pragma unroll 4
    for (int k4 = 0; k4 < DIN / 4; ++k4) {
        const float* wb = &Wl[(k4 * 4) * DOUT + jq * 4];
        float4 w0 = *(const float4*)(wb);
        float4 w1 = *(const float4*)(wb + DOUT);
        float4 w2 = *(const float4*)(wb + 2 * DOUT);
        float4 w3 = *(const float4*)(wb + 3 * DOUT);
#pragma unroll
        for (int i = 0; i < NPT; ++i) {
            float4 hv = h4[hb[i] + k4];
            acc[i].x += hv.x*w0.x + hv.y*w1.x + hv.z*w2.x + hv.w*w3.x;
            acc[i].y += hv.x*w0.y + hv.y*w1.y + hv.z*w2.y + hv.w*w3.y;
            acc[i].z += hv.x*w0.z + hv.y*w1.z + hv.z*w2.z + hv.w*w3.z;
            acc[i].w += hv.x*w0.w + hv.y*w1.w + hv.z*w2.w + hv.w*w3.w;
        }
    }
    float4 bv = ((const float4*)bias)[jq];
    float4 sv = {0,0,0,0}, qv = {0,0,0,0};
#pragma unroll
    for (int i = 0; i < NPT; ++i) {
        float4 a = acc[i];
        a.x += bv.x; a.y += bv.y; a.z += bv.z; a.w += bv.w;
        if (RELU) {
            a.x = fmaxf(a.x, 0.f); a.y = fmaxf(a.y, 0.f);
            a.z = fmaxf(a.z, 0.f); a.w = fmaxf(a.w, 0.f);
        }
        if (val[i]) {
            if (POOL) {
                int off = batch[node0 + i] - gbase;
                if (off < MAXG) {
                    atomicAdd(&pool_l[off * DOUT + jq * 4 + 0], (double)a.x);
                    atomicAdd(&pool_l[off * DOUT + jq * 4 + 1], (double)a.y);
                    atomicAdd(&pool_l[off * DOUT + jq * 4 + 2], (double)a.z);
                    atomicAdd(&pool_l[off * DOUT + jq * 4 + 3], (double)a.w);
                    if (jq == 0) atomicMax(&gmaxs, off);
                } else {
                    double* pg = &pooled[(size_t)(gbase + off) * DOUT + jq * 4];
                    atomicAdd(pg + 0, (double)a.x); atomicAdd(pg + 1, (double)a.y);
                    atomicAdd(pg + 2, (double)a.z); atomicAdd(pg + 3, (double)a.w);
                }
            } else if (F16OUT) {
                ushort4 o;
                o.x = f2h(a.x); o.y = f2h(a.y); o.z = f2h(a.z); o.w = f2h(a.w);
                *(ushort4*)((unsigned short*)m + (size_t)(node0 + i) * DOUT + (jq << 2)) = o;
            } else {
                ((float4*)m)[(size_t)(node0 + i) * TPN + jq] = a;
            }
            sv.x += a.x; sv.y += a.y; sv.z += a.z; sv.w += a.w;
            qv.x += a.x*a.x; qv.y += a.y*a.y; qv.z += a.z*a.z; qv.w += a.w*a.w;
        }
    }
    for (int off = TPN; off < 64; off <<= 1) {
        sv.x += __shfl_down(sv.x, off, 64); sv.y += __shfl_down(sv.y, off, 64);
        sv.z += __shfl_down(sv.z, off, 64); sv.w += __shfl_down(sv.w, off, 64);
        qv.x += __shfl_down(qv.x, off, 64); qv.y += __shfl_down(qv.y, off, 64);
        qv.z += __shfl_down(qv.z, off, 64); qv.w += __shfl_down(qv.w, off, 64);
    }
    int lane = tid & 63;
    if (lane < TPN) {
        atomicAdd(&ls[4*lane+0], (double)sv.x); atomicAdd(&ls[4*lane+1], (double)sv.y);
        atomicAdd(&ls[4*lane+2], (double)sv.z); atomicAdd(&ls[4*lane+3], (double)sv.w);
        atomicAdd(&lq[4*lane+0], (double)qv.x); atomicAdd(&lq[4*lane+1], (double)qv.y);
        atomicAdd(&lq[4*lane+2], (double)qv.z); atomicAdd(&lq[4*lane+3], (double)qv.w);
    }
    __syncthreads();
    int bkt = (blockIdx.x & (NBUCKET - 1)) * 256;
    if (tid < DOUT) {
        atomicAdd(&partOut[bkt + tid], ls[tid]);
        atomicAdd(&partOut[bkt + 128 + tid], lq[tid]);
    }
    if (POOL) {
        int gm = gmaxs;
        for (int i = tid; i < (gm + 1) * DOUT; i += 256) {
            double v = pool_l[i];
            if (v != 0.) atomicAdd(&pooled[(size_t)gbase * DOUT + i], v);
        }
    }
}

// ---------------- pool head: BN5(from stats) applied to pooled sums + MLP ----------------
__global__ void __launch_bounds__(128) k_poolhead(
        const double* __restrict__ pooled, const int* __restrict__ batch,
        const double* __restrict__ partIn, const float* __restrict__ gmv,
        const float* __restrict__ btv,
        const float* __restrict__ fc1w, const float* __restrict__ fc1b,
        const float* __restrict__ fc2w, const float* __restrict__ fc2b,
        float* __restrict__ out, int n) {
    __shared__ float pl[128];
    __shared__ float scs[128], shs[128];
    int g = blockIdx.x;
    int tid = threadIdx.x;
    bn_coef(partIn, gmv, btv, tid, n, scs, shs);
    int a = 0, b = n;
    while (a < b) { int mid = (a + b) >> 1; if (batch[mid] < g) a = mid + 1; else b = mid; }
    int lo = a;
    b = n;
    while (a < b) { int mid = (a + b) >> 1; if (batch[mid] < g + 1) a = mid + 1; else b = mid; }
    int hi = a;
    float cntf = (float)(hi - lo);
    float p = scs[tid] * (float)pooled[g * 128 + tid] + shs[tid] * cntf;
    pl[tid] = fmaxf(p, 0.f);
    __syncthreads();
    if (tid < 64) {
        float v1 = fc1b[tid];
        for (int k = 0; k < 128; ++k) v1 += pl[k] * fc1w[k * 64 + tid];
        v1 = fmaxf(v1, 0.f);
        float v = v1 * fc2w[tid];
        for (int off = 32; off > 0; off >>= 1) v += __shfl_down(v, off, 64);
        if (tid == 0) out[g] = v + fc2b[0];
    }
}

// ---------------- driver ----------------
extern "C" void kernel_launch(void* const* d_in, const int* in_sizes, int n_in,
                              void* d_out, int out_size, void* d_ws, size_t ws_size,
                              hipStream_t stream) {
    const float* x     = (const float*)d_in[0];
    const int*   ei    = (const int*)d_in[1];
    const float* ew    = (const float*)d_in[2];
    const int*   batch = (const int*)d_in[3];
    const float *W[5], *b[5], *gm[5], *bt[5];
    for (int i = 0; i < 5; ++i) {
        W[i]  = (const float*)d_in[4 + 4 * i];
        b[i]  = (const float*)d_in[5 + 4 * i];
        gm[i] = (const float*)d_in[6 + 4 * i];
        bt[i] = (const float*)d_in[7 + 4 * i];
    }
    const float* fc1w = (const float*)d_in[24];
    const float* fc1b = (const float*)d_in[25];
    const float* fc2w = (const float*)d_in[26];
    const float* fc2b = (const float*)d_in[27];
    float* out = (float*)d_out;

    // workspace layout
    char* wsb = (char*)d_ws;
    float* dis    = (float*)wsb;  wsb += sizeof(float) * NN;
    int*   ptr    = (int*)wsb;    wsb += sizeof(int) * (NN + 4);
    int*   bb     = (int*)wsb;    wsb += sizeof(int) * ABLK * NBKT;
    int*   totals = (int*)wsb;    wsb += sizeof(int) * (NBKT + 1);
    wsb = (char*)(((uintptr_t)wsb + 15) & ~(uintptr_t)15);
    double* part   = (double*)wsb;  wsb += sizeof(double) * 5 * PARTSZ;
    double* pooled = (double*)wsb;  wsb += sizeof(double) * NG * 128;
    int2*  staging= (int2*)wsb;   wsb += sizeof(int2) * NE;
    int2*  csr    = (int2*)wsb;   wsb += sizeof(int2) * NE;
    unsigned short* bufB1h = (unsigned short*)wsb; wsb += sizeof(unsigned short) * (size_t)NN * 64;
    unsigned short* bufB2h = (unsigned short*)wsb; wsb += sizeof(unsigned short) * (size_t)NN * 64;
    float* buf1   = (float*)wsb;  wsb += sizeof(float) * (size_t)NN * 64;    // gathers / m1
    float* buf2   = (float*)wsb;  wsb += sizeof(float) * (size_t)NN * 16;    // L1 out

    const int* row = ei;
    const int* col = ei + NE;
    const int B = 256;
    const int NBF = (NN + 15) / 16;       // fused F2 blocks
    const int GB1 = (NN + 127) / 128;     // gemm1 blocks
    const int ZN = 5 * PARTSZ + NG * 128; // part+pooled zero region (contiguous doubles)

    // prologue: bucketed CSR build; gemm1 overlapped with kA3 (independent work)
    kA1<<<ABLK, B, 0, stream>>>(col, bb, part, ZN, NE);
    kA2a<<<NBKT, B, 0, stream>>>(bb, totals);
    kA3g<<<ABLK + GB1, B, 0, stream>>>(row, col, ew, bb, totals, staging, x, W[0], buf1, NE, NN);
    kB<<<NBKT, B, 0, stream>>>(totals, staging, csr, ptr, dis, NN);

    // L1 gather (f64 acc): bias+relu+stats + CSR rescale write-back (fp32 weights)
    k_l1gather<<<(NN * 4 + 255) / 256, B, 0, stream>>>(buf1, ptr, csr, dis,
                                                       b[0], part + 0 * PARTSZ, buf2, NN);

    // F2: 16->32 fused, consume part[0] (BN1 hoisted), fp32 in, fp16 out
    k_fused<16, 32, 4, 1, 16><<<NBF, B, 0, stream>>>(
        buf2, ptr, csr, dis, part + 0 * PARTSZ, gm[0], bt[0],
        W[1], b[1], part + 1 * PARTSZ, bufB1h, NN);

    // L3: fp16 gather32 (BN2 hoisted, f64 acc) then gemm 32->64 (+relu, fp16 out)
    k_wgather<32, 1, 0><<<(int)(((long)NN * 16 + 255) / 256), B, 0, stream>>>(
        bufB1h, ptr, csr, dis, part + 1 * PARTSZ, gm[1], bt[1], buf1, NN);
    k_sgemm<32, 64, 1, 1, 0><<<(NN + 63) / 64, B, 0, stream>>>(
        buf1, W[2], b[2], part + 2 * PARTSZ, bufB2h, nullptr, nullptr, NN);

    // L4: fp16 gather64 (BN3 hoisted) then gemm 64->64 (no relu; BN4 stats, fp16 out)
    k_wgather<64, 1, 0><<<(int)(((long)NN * 32 + 255) / 256), B, 0, stream>>>(
        bufB2h, ptr, csr, dis, part + 2 * PARTSZ, gm[2], bt[2], buf1, NN);
    k_sgemm<64, 64, 0, 1, 0><<<(NN + 63) / 64, B, 0, stream>>>(
        buf1, W[3], b[3], part + 3 * PARTSZ, bufB1h, nullptr, nullptr, NN);

    // L5: fp16 gather64 (per-edge relu(BN4)) then gemm 64->128 fused with pool (f64 sums)
    k_wgather<64, 0, 1><<<(int)(((long)NN * 32 + 255) / 256), B, 0, stream>>>(
        bufB1h, ptr, csr, dis, part + 3 * PARTSZ, gm[3], bt[3], buf1, NN);
    k_sgemm<64, 128, 0, 0, 1><<<(NN + 31) / 32, B, 0, stream>>>(
        buf1, W[4], b[4], part + 4 * PARTSZ, nullptr, batch, pooled, NN);

    // head: BN5 (stats from part[4]) on pooled sums + MLP
    k_poolhead<<<NG, 128, 0, stream>>>(pooled, batch, part + 4 * PARTSZ, gm[4], bt[4],
                                       fc1w, fc1b, fc2w, fc2b, out, NN);
}